// Round 11
// baseline (690.154 us; speedup 1.0000x reference)
//
#include <hip/hip_runtime.h>

// ============================================================================
// ImprovedMoE R29 = R28 with the HEAD=1 bug fixed: the fused-cls dot region
// covered 320 work items with `if (tid < 320)` but blocks have 256 threads,
// so batches 26..31 per tile got garbage logits/entropy (absmax 1.6). Now a
// block-stride loop. HEAD=2 (gate) was already exact (4x256=1024).
// Everything else identical to R28: heads fused into gate1/exp3 epilogues,
// heads_small_k deleted, R27 trunk untouched.
// ============================================================================

typedef _Float16 h16;
typedef _Float16 half8 __attribute__((ext_vector_type(8)));
typedef float f32x16 __attribute__((ext_vector_type(16)));

__device__ __forceinline__ void split2f(float x, h16& hh, h16& ll) {
  h16 a = (h16)x;
  hh = a;
  ll = (h16)(x - (float)a);
}

__device__ __forceinline__ void dma_b16(const h16* g, h16* l) {
  __builtin_amdgcn_global_load_lds(
      (const __attribute__((address_space(1))) void*)g,
      (__attribute__((address_space(3))) void*)l, 16, 0, 0);
}

// ---- fused prep: zero pads + conv1 wt transpose + conv2..6 weight split ----
__global__ void prep_all_k(const float* __restrict__ cw1, const float* __restrict__ cw2,
                           const float* __restrict__ cw3, const float* __restrict__ cw4,
                           const float* __restrict__ cw5, const float* __restrict__ cw6,
                           float* __restrict__ wt1t, h16* __restrict__ wh,
                           h16* p0, h16* p1, h16* p2, h16* p3) {
  int idx = blockIdx.x * 256 + threadIdx.x;
  if (idx < 64) {
    h16* p = (idx < 16) ? p0 : (idx < 32) ? p1 : (idx < 48) ? p2 : p3;
    p[idx & 15] = (h16)0.f;
    return;
  }
  idx -= 64;
  if (idx < 1728) {
    int co = idx % 64, r = idx / 64;
    wt1t[idx] = cw1[(size_t)co * 27 + r];
    return;
  }
  idx -= 1728;
  const float* w; int CIN, COUT; size_t off;
  if (idx < 36864)        { w = cw2; CIN = 64;  COUT = 64;  off = 0; }
  else if (idx < 110592)  { w = cw3; CIN = 64;  COUT = 128; off = 36864;  idx -= 36864; }
  else if (idx < 258048)  { w = cw4; CIN = 128; COUT = 128; off = 110592; idx -= 110592; }
  else if (idx < 552960)  { w = cw5; CIN = 128; COUT = 256; off = 258048; idx -= 258048; }
  else if (idx < 1142784) { w = cw6; CIN = 256; COUT = 256; off = 552960; idx -= 552960; }
  else return;
  int KCOB = COUT >> 6;
  int lidx = idx;
  int c8   = idx & 7;
  int t    = idx >> 3;
  int co64 = t & 63;  t >>= 6;
  int half = t & 1;   t >>= 1;
  int cob  = t % KCOB; t /= KCOB;
  int tap  = t % 9;
  int ck   = t / 9;
  int ci = ck * 16 + half * 8 + c8;
  int co = cob * 64 + co64;
  float v = w[((size_t)co * CIN + ci) * 9 + tap];
  wh[off + lidx] = (h16)v;
}

// ---- conv1: 3->64, 32x32, fp32 vector; outputs blocked hi/lo planes (+16) ----
__global__ __launch_bounds__(256) void conv1_k(
    const float* __restrict__ x, const float* __restrict__ wt,
    const float* __restrict__ cb, const float* __restrict__ bns,
    const float* __restrict__ bnb, h16* __restrict__ oh, h16* __restrict__ ol)
{
  __shared__ float sx[3 * 34 * 34];
  const int tid = threadIdx.x;
  const int img = blockIdx.x;
  for (int idx = tid; idx < 3 * 34 * 34; idx += 256) {
    int xx = idx % 34;
    int t  = idx / 34;
    int rr = t % 34;
    int c  = t / 34;
    int gr = rr - 1, gx = xx - 1;
    float v = 0.f;
    if (gr >= 0 && gr < 32 && gx >= 0 && gx < 32)
      v = x[((size_t)(img * 3 + c) * 32 + gr) * 32 + gx];
    sx[(c * 34 + rr) * 34 + xx] = v;
  }
  __syncthreads();
#pragma unroll 1
  for (int k = 0; k < 4; ++k) {
    int px = k * 256 + tid;
    int yy = px >> 5, xx = px & 31;
    float in27[27];
#pragma unroll
    for (int c = 0; c < 3; ++c)
#pragma unroll
      for (int dy = 0; dy < 3; ++dy)
#pragma unroll
        for (int dx = 0; dx < 3; ++dx)
          in27[c * 9 + dy * 3 + dx] = sx[(c * 34 + yy + dy) * 34 + xx + dx];
#pragma unroll 1
    for (int cbk = 0; cbk < 4; ++cbk) {
      h16 hb[16], lb[16];
#pragma unroll
      for (int j = 0; j < 16; ++j) {
        int co = cbk * 16 + j;
        float acc = 0.f;
#pragma unroll
        for (int t = 0; t < 27; ++t) acc = fmaf(in27[t], wt[t * 64 + co], acc);
        float s = bns[co];
        float yv = fmaxf(fmaf(acc + cb[co], s, bnb[co]), 0.f);
        split2f(yv, hb[j], lb[j]);
      }
      size_t o = 16 + ((size_t)(img * 4 + cbk) * 1024 + px) * 16;
      *(half8*)&oh[o]     = *(half8*)&hb[0];
      *(half8*)&oh[o + 8] = *(half8*)&hb[8];
      *(half8*)&ol[o]     = *(half8*)&lb[0];
      *(half8*)&ol[o + 8] = *(half8*)&lb[8];
    }
  }
}

// ---------------------------------------------------------------------------
// MFMA conv: 3x3 SAME, tap-decomposed implicit GEMM. D = (Ah+Al)*Bh.
// (R27 structure: HSPLIT everywhere, clamped halo staging, BREG, DBUF/KU.)
// ---------------------------------------------------------------------------
template<int H, int W, int CIN, int COUT, int MT, int POOL, int OCC, int DBUF,
         int BREG, int KU>
__global__ __launch_bounds__(256, OCC) void conv_mfma(
    const h16* __restrict__ Ah, const h16* __restrict__ Al,
    const h16* __restrict__ Wh,
    const float* __restrict__ cb, const float* __restrict__ bns,
    const float* __restrict__ bnb,
    h16* __restrict__ Oh, h16* __restrict__ Ol, float* __restrict__ feats)
{
  constexpr int TPI  = (H * W) / 32;
  constexpr int RPT  = 32 / W;
  constexpr int IPB  = (4 * MT * 32 >= H * W) ? (4 * MT * 32) / (H * W) : 1;
  constexpr int KC   = CIN / 16;
  constexpr int HW   = H * W;
  constexpr int KCO  = COUT / 16;
  constexpr int KCOB = COUT / 64;
  constexpr int LOGW = (W == 32) ? 5 : (W == 16) ? 4 : 3;
  constexpr int ROWS_COV = (4 * MT * 32) / (W * IPB);   // rows covered / image
  constexpr int ROFF  = (ROWS_COV < H) ? 1 : 0;          // staged halo rows
  constexpr int SROWS = ROWS_COV + 2 * ROFF;
  constexpr int ASZ = IPB * SROWS * W * 16;              // h16 per plane
  constexpr int ACH = ASZ / 8;                           // 16B chunks/plane
  constexpr int ACH2 = ACH / 2;                          // chunks/(plane,hs)
  constexpr int NBUF = DBUF ? 2 : 1;
  constexpr int TCH  = BREG ? (KU * 2 * ACH) : (1152 + 2 * ACH); // chunks/stage
  constexpr int NI   = (TCH + 255) / 256;
  constexpr int SBH  = 9 * 2 * 64 * 8;                   // h16 per sB buffer
  constexpr int SBSZ = BREG ? 8 : (NBUF * SBH);

  __shared__ h16 sB[SBSZ];
  __shared__ h16 sA[NBUF][KU][2][ASZ + 16];              // +16 = zero sentinel

  const int tid  = threadIdx.x;
  const int lane = tid & 63;
  const int wave = tid >> 6;
  const int half = lane >> 5;
  const int col  = lane & 31;
  const int cob  = blockIdx.z;
  const int co0  = cob * 64;
  const int r0img = blockIdx.y * ROWS_COV;

  auto stageA = [&](int ck, int nb, int ku, int cc2) {
    int pl = cc2 / ACH;
    int cc = cc2 - pl * ACH;             // linear LDS dest chunk (required)
    // HSPLIT [hs][px] sub-planes; ACH2 % 64 == 0 -> hs wave-uniform.
    int hs  = cc / ACH2;
    int px  = cc - hs * ACH2;
    int iL  = px / (SROWS * W);
    int rem = px - iL * (SROWS * W);
    int rs  = rem / W;
    int pxx = rem - rs * W;
    int grow = r0img + rs - ROFF;
    if constexpr (ROFF == 1) {
      // CLAMP (not skip): all lanes stay active -> no exec divergence.
      grow = grow < 0 ? 0 : (grow >= H ? H - 1 : grow);
    }
    const h16* gp = pl ? Al : Ah;
    int srcA = 16 + (((blockIdx.x * IPB + iL) * KC + ck) * HW + grow * W + pxx) * 16 + hs * 8;
    dma_b16(gp + srcA, &sA[nb][ku][pl][cc * 8]);
  };

  auto STAGE = [&](int ck0, int nb) {
#pragma unroll
    for (int i = 0; i < NI; ++i) {
      int id = tid + i * 256;
      if constexpr (BREG) {
        if (id < TCH) {
          int ku = id / (2 * ACH);
          stageA(ck0 + ku, nb, ku, id - ku * 2 * ACH);
        }
      } else {
        if (id < 1152) {
          int src = ((ck0 * 9 + (id >> 7)) * KCOB + cob) * 1024 + (id & 127) * 8;
          dma_b16(Wh + src, &sB[nb * SBH + id * 8]);
        } else if (id < TCH) {
          stageA(ck0, nb, 0, id - 1152);
        }
      }
    }
  };

  int scc[MT], ty[MT], tx[MT], img_t[MT], rw0[MT];
#pragma unroll
  for (int t = 0; t < MT; ++t) {
    int gt   = blockIdx.y * (4 * MT) + wave * MT + t;
    int imgL = (gt / TPI) % IPB;
    int img  = blockIdx.x * IPB + gt / TPI;
    int row0 = (gt % TPI) * RPT;
    int y = row0 + (col >> LOGW);
    int x = col & (W - 1);
    img_t[t] = img; rw0[t] = row0; ty[t] = y; tx[t] = x;
    scc[t] = half * ACH2 + (imgL * SROWS + (y - r0img + ROFF)) * W + x;  // chunk
  }

  f32x16 acc[MT][2];
#pragma unroll
  for (int t = 0; t < MT; ++t)
#pragma unroll
    for (int n = 0; n < 2; ++n)
#pragma unroll
      for (int i = 0; i < 16; ++i) acc[t][n][i] = 0.f;

  // zero the halo sentinels + stage stage-0 into buffer 0
  if (tid < NBUF * KU * 2 * 16) {
    int wsl = tid >> 4;                  // [nb][ku][pl] slot
    int pl = wsl & 1;
    int kq = (wsl >> 1) % KU;
    int nb = (wsl >> 1) / KU;
    sA[nb][kq][pl][ASZ + (tid & 15)] = (h16)0.f;
  }
  STAGE(0, 0);
  __syncthreads();

  const int zoff = ASZ + half * 8;   // sentinel (h16 offset)

  int buf = 0;
#pragma unroll 1
  for (int cc = 0; cc < KC; cc += KU) {
    if constexpr (DBUF) {
      if (cc + KU < KC) STAGE(cc + KU, buf ^ 1);   // lands under the tap loops
    }
#pragma unroll
    for (int ku = 0; ku < KU; ++ku) {
      const int ck = cc + ku;
      const h16* bB = &sB[BREG ? 0 : (buf * SBH)];
      const h16* aH = &sA[buf][ku][0][0];
      const h16* aL = &sA[buf][ku][1][0];
      const h16* bG = Wh + ((size_t)ck * 9 * KCOB + cob) * 1024 + half * 512;

#pragma unroll
      for (int tap = 0; tap < 9; ++tap) {
        const int dy = tap / 3 - 1, dx = tap % 3 - 1;
        const int dsh = dy * W + dx;          // pixel (=chunk) delta
        half8 bh[2];
        if constexpr (BREG) {
          const h16* bt = bG + (size_t)tap * KCOB * 1024;
          bh[0] = *(const half8*)&bt[col * 8];
          bh[1] = *(const half8*)&bt[(32 + col) * 8];
        } else {
#pragma unroll
          for (int n = 0; n < 2; ++n)
            bh[n] = *(const half8*)&bB[((tap * 2 + half) * 64 + n * 32 + col) * 8];
        }
        half8 ah[MT], al[MT];
#pragma unroll
        for (int t = 0; t < MT; ++t) {
          bool v = ((unsigned)(ty[t] + dy) < (unsigned)H) &&
                   ((unsigned)(tx[t] + dx) < (unsigned)W);
          int po = v ? ((scc[t] + dsh) * 8) : zoff;
          ah[t] = *(const half8*)(aH + po);
          al[t] = *(const half8*)(aL + po);
        }
#pragma unroll
        for (int t = 0; t < MT; ++t)
#pragma unroll
          for (int n = 0; n < 2; ++n) {
            acc[t][n] = __builtin_amdgcn_mfma_f32_32x32x16_f16(ah[t], bh[n], acc[t][n], 0, 0, 0);
            acc[t][n] = __builtin_amdgcn_mfma_f32_32x32x16_f16(al[t], bh[n], acc[t][n], 0, 0, 0);
          }
      }
    }

    if constexpr (DBUF) {
      __syncthreads();   // drains the DMA (vmcnt) + orders buffer swap
      buf ^= 1;
    } else {
      __syncthreads();   // all waves done reading sA/sB
      if (cc + KU < KC) {
        STAGE(cc + KU, 0);
        __syncthreads(); // drains DMA -> buffers hold next stage
      }
    }
  }

#pragma unroll
  for (int n = 0; n < 2; ++n) {
    const int co = co0 + n * 32 + col;
    const float es = bns[co];
    const float eb = fmaf(cb[co], es, bnb[co]);
    const int cko = co >> 4, c16 = co & 15;

    if constexpr (POOL == 0) {
#pragma unroll
      for (int t = 0; t < MT; ++t) {
#pragma unroll
        for (int r = 0; r < 16; ++r) {
          float v = fmaxf(fmaf(acc[t][n][r], es, eb), 0.f);
          int m = (r & 3) + 4 * half + 8 * (r >> 2);
          int y = rw0[t] + (m >> LOGW);
          int x = m & (W - 1);
          size_t oi = 16 + ((size_t)(img_t[t] * KCO + cko) * HW + y * W + x) * 16 + c16;
          h16 hh, ll; split2f(v, hh, ll);
          Oh[oi] = hh; Ol[oi] = ll;
        }
      }
    } else if constexpr (POOL == 1 && RPT == 1) {
      constexpr int HWq = (H / 2) * (W / 2);
#pragma unroll
      for (int tp = 0; tp < MT / 2; ++tp) {
        const int t0 = 2 * tp, t1 = 2 * tp + 1;
        const int yq = rw0[t0] >> 1;
#pragma unroll
        for (int r = 0; r < 16; r += 2) {
          float v00 = fmaxf(fmaf(acc[t0][n][r],     es, eb), 0.f);
          float v01 = fmaxf(fmaf(acc[t0][n][r + 1], es, eb), 0.f);
          float v10 = fmaxf(fmaf(acc[t1][n][r],     es, eb), 0.f);
          float v11 = fmaxf(fmaf(acc[t1][n][r + 1], es, eb), 0.f);
          float mv = fmaxf(fmaxf(v00, v01), fmaxf(v10, v11));
          int xq = ((r & 3) >> 1) + 2 * half + 4 * (r >> 2);
          size_t oi = 16 + ((size_t)(img_t[t0] * KCO + cko) * HWq + yq * (W / 2) + xq) * 16 + c16;
          h16 hh, ll; split2f(mv, hh, ll);
          Oh[oi] = hh; Ol[oi] = ll;
        }
      }
    } else if constexpr (POOL == 1) {
      constexpr int HWq = (H / 2) * (W / 2);
#pragma unroll
      for (int t = 0; t < MT; ++t) {
        const int yq = rw0[t] >> 1;
#pragma unroll
        for (int r = 0; r < 8; r += 2) {
          float v00 = fmaxf(fmaf(acc[t][n][r],     es, eb), 0.f);
          float v01 = fmaxf(fmaf(acc[t][n][r + 1], es, eb), 0.f);
          float v10 = fmaxf(fmaf(acc[t][n][r + 8], es, eb), 0.f);
          float v11 = fmaxf(fmaf(acc[t][n][r + 9], es, eb), 0.f);
          float mv = fmaxf(fmaxf(v00, v01), fmaxf(v10, v11));
          int xq = ((r & 3) >> 1) + 2 * half + 4 * (r >> 2);
          size_t oi = 16 + ((size_t)(img_t[t] * KCO + cko) * HWq + yq * (W / 2) + xq) * 16 + c16;
          h16 hh, ll; split2f(mv, hh, ll);
          Oh[oi] = hh; Ol[oi] = ll;
        }
      }
    } else if constexpr (POOL == 2 && MT == 1) {
      // reuse sA[0] as the reduction scratch (all reads drained by last barrier)
      float* sRd = (float*)&sA[0][0][0][0];
      float s = 0.f;
#pragma unroll
      for (int r = 0; r < 16; ++r)
        s += fmaxf(fmaf(acc[0][n][r], es, eb), 0.f);
      s += __shfl_xor(s, 32, 64);
      if (half == 0) sRd[wave * 64 + n * 32 + col] = s;
    } else if constexpr (POOL == 2) {
      float s = 0.f;
#pragma unroll
      for (int t = 0; t < MT; ++t)
#pragma unroll
        for (int r = 0; r < 16; ++r)
          s += fmaxf(fmaf(acc[t][n][r], es, eb), 0.f);
      s += __shfl_xor(s, 32, 64);
      if (half == 0) feats[(size_t)img_t[0] * 256 + co] = s * (1.f / 64.f);
    }
  }

  if constexpr (POOL == 2 && MT == 1) {
    float* sRd = (float*)&sA[0][0][0][0];
    __syncthreads();
    if (tid < 128) {
      int li = tid >> 6, co_l = tid & 63;
      float s = sRd[(li * 2) * 64 + co_l] + sRd[(li * 2 + 1) * 64 + co_l];
      feats[(size_t)(blockIdx.x * 2 + li) * 256 + co0 + co_l] = s * (1.f / 64.f);
    }
  }
}

// ---------------------------------------------------------------------------
// Batched head GEMM: 32 batch rows/block, one expert per blockIdx.y.
// HEAD=0: plain (store out). HEAD=1: + cls logits/softmax/entropy fused
// (out store dropped; writes o1=logits_e, o2=conf). HEAD=2: + gate2/gate3
// fused (out store dropped; writes o1=scores).
// ---------------------------------------------------------------------------
template<int O, int K, int LN, int RELU, int HEAD>
__global__ __launch_bounds__(256, 4) void gemm_head(
    const float* __restrict__ A, size_t aStrideE,
    const float* __restrict__ Wm, const float* __restrict__ bias,
    const float* __restrict__ g, const float* __restrict__ bb,
    float* __restrict__ out,
    const float* __restrict__ xw1, const float* __restrict__ xb1,
    const float* __restrict__ xw2, const float* __restrict__ xb2,
    float* __restrict__ o1, float* __restrict__ o2)
{
  constexpr int KC  = (O >= 256) ? 32 : 64;
  constexpr int WST = O + 4;
  constexpr int TO  = O / 16;
  __shared__ float sA[KC * 36];
  __shared__ float sW[KC * WST];
  __shared__ float mArr[32], rArr[32];

  const int tid  = threadIdx.x;
  const int lane = tid & 63;
  const int wave = tid >> 6;
  const int e    = blockIdx.y;
  const int b0g  = blockIdx.x * 32;
  const int bl   = (lane & 15) * 2;
  const int ol   = wave * (O / 4) + (lane >> 4) * TO;

  const float* Ae = A + (size_t)e * aStrideE;
  const float* We = Wm + (size_t)e * O * K;

  float acc[2][TO];
#pragma unroll
  for (int i = 0; i < 2; ++i)
#pragma unroll
    for (int j = 0; j < TO; ++j) acc[i][j] = 0.f;

  for (int k0 = 0; k0 < K; k0 += KC) {
    for (int idx = tid; idx < 32 * KC; idx += 256) {
      int kk = idx % KC, bb_ = idx / KC;
      sA[kk * 36 + bb_] = Ae[(size_t)(b0g + bb_) * K + k0 + kk];
    }
    for (int idx = tid; idx < O * KC; idx += 256) {
      int kk = idx % KC, oo = idx / KC;
      sW[kk * WST + oo] = We[(size_t)oo * K + k0 + kk];
    }
    __syncthreads();
#pragma unroll 4
    for (int kk = 0; kk < KC; ++kk) {
      float2 av = *(const float2*)&sA[kk * 36 + bl];
      float a2[2] = {av.x, av.y};
#pragma unroll
      for (int j4 = 0; j4 < TO; j4 += 4) {
        float4 wv = *(const float4*)&sW[kk * WST + ol + j4];
        float w4[4] = {wv.x, wv.y, wv.z, wv.w};
#pragma unroll
        for (int i = 0; i < 2; ++i)
#pragma unroll
          for (int jj = 0; jj < 4; ++jj)
            acc[i][j4 + jj] = fmaf(a2[i], w4[jj], acc[i][j4 + jj]);
      }
    }
    __syncthreads();
  }

  const float* bi = bias + (size_t)e * O;
#pragma unroll
  for (int i = 0; i < 2; ++i)
#pragma unroll
    for (int j = 0; j < TO; ++j) acc[i][j] += bi[ol + j];

  if constexpr (LN) {
    float* redS = sA;
    float* redQ = sA + 512;
    const int grp = wave * 4 + (lane >> 4);
#pragma unroll
    for (int i = 0; i < 2; ++i) {
      float s = 0.f, q = 0.f;
#pragma unroll
      for (int j = 0; j < TO; ++j) { s += acc[i][j]; q += acc[i][j] * acc[i][j]; }
      redS[(bl + i) * 16 + grp] = s;
      redQ[(bl + i) * 16 + grp] = q;
    }
    __syncthreads();
    if (tid < 32) {
      float s = 0.f, q = 0.f;
#pragma unroll
      for (int gi = 0; gi < 16; ++gi) { s += redS[tid * 16 + gi]; q += redQ[tid * 16 + gi]; }
      float mean = s * (1.f / O);
      float var  = q * (1.f / O) - mean * mean;
      mArr[tid] = mean;
      rArr[tid] = rsqrtf(var + 1e-5f);
    }
    __syncthreads();
    const float* gp  = g + (size_t)e * O;
    const float* bbp = bb + (size_t)e * O;
#pragma unroll
    for (int i = 0; i < 2; ++i) {
      float mean = mArr[bl + i], rstd = rArr[bl + i];
#pragma unroll
      for (int j = 0; j < TO; ++j)
        acc[i][j] = (acc[i][j] - mean) * rstd * gp[ol + j] + bbp[ol + j];
    }
  }
  if constexpr (RELU) {
#pragma unroll
    for (int i = 0; i < 2; ++i)
#pragma unroll
      for (int j = 0; j < TO; ++j) acc[i][j] = fmaxf(acc[i][j], 0.f);
  }

  if constexpr (HEAD == 0) {
#pragma unroll
    for (int i = 0; i < 2; ++i) {
      float* op = out + ((size_t)e * 512 + b0g + bl + i) * O + ol;
#pragma unroll
      for (int j4 = 0; j4 < TO; j4 += 4)
        *(float4*)(op + j4) = make_float4(acc[i][j4], acc[i][j4 + 1], acc[i][j4 + 2], acc[i][j4 + 3]);
    }
  } else if constexpr (HEAD == 1) {
    // ---- fused cls: logits (lg), softmax entropy -> conf. emb not stored.
    float* et = sW;                      // 32 x WST tile (sW is free here)
    __syncthreads();                     // all sW reads of the K loop done
#pragma unroll
    for (int i = 0; i < 2; ++i)
#pragma unroll
      for (int j = 0; j < TO; ++j) et[(bl + i) * WST + ol + j] = acc[i][j];
    __syncthreads();
    // 320 work items (32 b x 10 o) on 256 threads: block-stride loop.
    for (int idx = tid; idx < 320; idx += 256) {
      int b = idx / 10, o = idx - (idx / 10) * 10;
      const float* wp = xw1 + ((size_t)e * 10 + o) * O;
      const float* er = et + b * WST;
      float s = 0.f;
      for (int c = 0; c < O; ++c) s = fmaf(er[c], wp[c], s);
      s += xb1[e * 10 + o];
      o1[((size_t)(b0g + b) * 16 + e) * 10 + o] = s;
      sA[b * 10 + o] = s;
    }
    __syncthreads();
    if (tid < 32) {
      int b = tid;
      float l0[10];
#pragma unroll
      for (int o = 0; o < 10; ++o) l0[o] = sA[b * 10 + o];
      float m = l0[0];
#pragma unroll
      for (int o = 1; o < 10; ++o) m = fmaxf(m, l0[o]);
      float p0[10], sum = 0.f;
#pragma unroll
      for (int o = 0; o < 10; ++o) { p0[o] = expf(l0[o] - m); sum += p0[o]; }
      float inv = 1.f / sum, ent = 0.f;
#pragma unroll
      for (int o = 0; o < 10; ++o) { float pp = p0[o] * inv; ent -= pp * logf(pp + 1e-12f); }
      o2[(size_t)(b0g + b) * 16 + e] = -ent;
    }
  } else {
    // ---- fused gate2 (1024 parallel 64-dots) + gate3 -> scores. g1 not stored.
    float* gt = sW;                      // 32 x WST tile
    __syncthreads();
#pragma unroll
    for (int i = 0; i < 2; ++i)
#pragma unroll
      for (int j = 0; j < TO; ++j) gt[(bl + i) * WST + ol + j] = acc[i][j];
    __syncthreads();
#pragma unroll
    for (int p = 0; p < 4; ++p) {
      int idx = tid + p * 256;           // 1024 (b, o2) pairs
      int b = idx >> 5, o2i = idx & 31;
      const float* wr = xw1 + ((size_t)e * 32 + o2i) * 64;
      const float* gr = gt + b * WST;
      float s = 0.f;
      for (int c = 0; c < 64; ++c) s = fmaf(gr[c], wr[c], s);
      sA[b * 36 + o2i] = fmaxf(s + xb1[e * 32 + o2i], 0.f);
    }
    __syncthreads();
    if (tid < 32) {
      int b = tid;
      const float* w3p = xw2 + e * 32;
      float s = 0.f;
#pragma unroll
      for (int oo = 0; oo < 32; ++oo) s = fmaf(sA[b * 36 + oo], w3p[oo], s);
      o1[(size_t)(b0g + b) * 16 + e] = s + xb2[e];
    }
  }
}

__global__ void routing_k(const float* __restrict__ scores, const float* __restrict__ conf,
                          const float* __restrict__ logits_e, float* __restrict__ out)
{
  __shared__ int t2[512];
  __shared__ int chs[512];
  const int tid = threadIdx.x;

  if (tid < 512) {
    int b = tid;
    float v0 = -3.4e38f, v1 = -3.4e38f;
    int i0 = 0, i1 = 0;
#pragma unroll
    for (int e = 0; e < 16; ++e) {
      float s = scores[b * 16 + e];
      float c = conf[b * 16 + e];
      float v = 0.7f * s + 0.3f * c - 0.125f;
      out[5120 + b * 16 + e] = v;
      if (v > v0) { v1 = v0; i1 = i0; v0 = v; i0 = e; }
      else if (v > v1) { v1 = v; i1 = e; }
    }
    t2[b] = i0 | (i1 << 8);
  }
  __syncthreads();

  if (tid < 64) {
    int lane = tid;
    int cnt = 0;
    int pk[8];
#pragma unroll
    for (int k = 0; k < 8; ++k) pk[k] = t2[k * 64 + lane];
#pragma unroll 1
    for (int k = 0; k < 8; ++k) {
      for (int j = 0; j < 64; ++j) {
        int pair = __shfl(pk[k], j, 64);
        int i0 = pair & 0xff, i1 = (pair >> 8) & 0xff;
        int c0 = __shfl(cnt, i0, 64);
        int c1 = __shfl(cnt, i1, 64);
        int ch = (c0 < 64) ? i0 : ((c1 < 64) ? i1 : ((c0 <= c1) ? i0 : i1));
        cnt += (lane == ch) ? 1 : 0;
        if (lane == 0) chs[k * 64 + j] = ch;
      }
    }
  }
  __syncthreads();

  if (tid < 512) {
    int b = tid;
    int ch = chs[b];
#pragma unroll
    for (int e = 0; e < 16; ++e)
      out[13312 + b * 16 + e] = (e == ch) ? 1.0f : 0.0f;
#pragma unroll
    for (int o = 0; o < 10; ++o)
      out[b * 10 + o] = logits_e[((size_t)b * 16 + ch) * 10 + o];
  }
}

// ============================================================================
extern "C" void kernel_launch(void* const* d_in, const int* in_sizes, int n_in,
                              void* d_out, int out_size, void* d_ws, size_t ws_size,
                              hipStream_t stream) {
  (void)in_sizes; (void)n_in; (void)out_size; (void)ws_size;

  const float* x = (const float*)d_in[0];
  const float *cw[6], *cbv[6], *bsv[6], *bbv[6];
  for (int i = 0; i < 6; ++i) {
    cw[i]  = (const float*)d_in[1 + 4 * i];
    cbv[i] = (const float*)d_in[2 + 4 * i];
    bsv[i] = (const float*)d_in[3 + 4 * i];
    bbv[i] = (const float*)d_in[4 + 4 * i];
  }
  const float* gate_w1  = (const float*)d_in[25];
  const float* gate_b1  = (const float*)d_in[26];
  const float* gate_g1  = (const float*)d_in[27];
  const float* gate_bb1 = (const float*)d_in[28];
  const float* gate_w2  = (const float*)d_in[29];
  const float* gate_b2  = (const float*)d_in[30];
  const float* gate_w3  = (const float*)d_in[31];
  const float* gate_b3  = (const float*)d_in[32];
  const float* exp_w1   = (const float*)d_in[33];
  const float* exp_b1   = (const float*)d_in[34];
  const float* exp_g1   = (const float*)d_in[35];
  const float* exp_bb1  = (const float*)d_in[36];
  const float* exp_w2   = (const float*)d_in[37];
  const float* exp_b2   = (const float*)d_in[38];
  const float* exp_g2   = (const float*)d_in[39];
  const float* exp_bb2  = (const float*)d_in[40];
  const float* exp_w3   = (const float*)d_in[41];
  const float* exp_b3   = (const float*)d_in[42];
  const float* cls_w    = (const float*)d_in[43];
  const float* cls_b    = (const float*)d_in[44];

  char* wsb = (char*)d_ws;
  const size_t off_wt1t = 0;
  const size_t off_whi  = 6912;
  const size_t off_Phi  = 4578048;
  const size_t off_Plo  = 71687168;
  const size_t off_Qhi  = 138796288;
  const size_t off_Qlo  = 155573760;
  const size_t off_feats= 172351232;
  const size_t off_h1   = 138796288 + 512;
  const size_t off_h2   = off_h1 + 8388608;
  const size_t off_emb  = off_h2 + 4194304;
  const size_t off_g1   = off_emb + 4194304;
  const size_t off_lg   = off_g1 + 2097152;
  const size_t off_conf = off_lg + 327680;
  const size_t off_sc   = off_conf + 32768;

  float* wt1t = (float*)(wsb + off_wt1t);
  h16* whi = (h16*)(wsb + off_whi);
  h16* Phi = (h16*)(wsb + off_Phi);
  h16* Plo = (h16*)(wsb + off_Plo);
  h16* Qhi = (h16*)(wsb + off_Qhi);
  h16* Qlo = (h16*)(wsb + off_Qlo);
  float* feats = (float*)(wsb + off_feats);
  float* h1 = (float*)(wsb + off_h1);
  float* h2 = (float*)(wsb + off_h2);
  float* emb = (float*)(wsb + off_emb);
  float* lg = (float*)(wsb + off_lg);
  float* conf = (float*)(wsb + off_conf);
  float* sc = (float*)(wsb + off_sc);

  const size_t wo2 = 0;
  const size_t wo3 = 36864;
  const size_t wo4 = 110592;
  const size_t wo5 = 258048;
  const size_t wo6 = 552960;

  // ---- fused prep (pads + wt1 transpose + all weight splits) ----
  prep_all_k<<<4471, 256, 0, stream>>>(cw[0], cw[1], cw[2], cw[3], cw[4], cw[5],
                                       wt1t, whi, Phi, Plo, Qhi, Qlo);

  // ---- trunk ----
  conv1_k<<<512, 256, 0, stream>>>(x, wt1t, cbv[0], bsv[0], bbv[0], Phi, Plo);
  // <H, W, CIN, COUT, MT, POOL, OCC, DBUF, BREG, KU>
  conv_mfma<32, 32, 64, 64, 2, 1, 3, 1, 1, 1><<<dim3(512, 4, 1), 256, 0, stream>>>(
      Phi, Plo, whi + wo2, cbv[1], bsv[1], bbv[1], Qhi, Qlo, nullptr);
  conv_mfma<16, 16, 64, 128, 2, 0, 3, 1, 1, 1><<<dim3(512, 1, 2), 256, 0, stream>>>(
      Qhi, Qlo, whi + wo3, cbv[2], bsv[2], bbv[2], Phi, Plo, nullptr);
  conv_mfma<16, 16, 128, 128, 2, 1, 3, 1, 1, 1><<<dim3(512, 1, 2), 256, 0, stream>>>(
      Phi, Plo, whi + wo4, cbv[3], bsv[3], bbv[3], Qhi, Qlo, nullptr);
  conv_mfma<8, 8, 128, 256, 1, 0, 3, 1, 1, 1><<<dim3(256, 1, 4), 256, 0, stream>>>(
      Qhi, Qlo, whi + wo5, cbv[4], bsv[4], bbv[4], Phi, Plo, nullptr);
  conv_mfma<8, 8, 256, 256, 1, 2, 4, 1, 1, 2><<<dim3(256, 1, 4), 256, 0, stream>>>(
      Phi, Plo, whi + wo6, cbv[5], bsv[5], bbv[5], nullptr, nullptr, feats);

  // ---- experts + gates (heads fused into gate1/exp3 epilogues) ----
  gemm_head<256, 256, 1, 1, 0><<<dim3(16, 16), 256, 0, stream>>>(
      feats, (size_t)0, exp_w1, exp_b1, exp_g1, exp_bb1, h1,
      nullptr, nullptr, nullptr, nullptr, nullptr, nullptr);
  gemm_head<64, 256, 1, 1, 2><<<dim3(16, 16), 256, 0, stream>>>(
      feats, (size_t)0, gate_w1, gate_b1, gate_g1, gate_bb1, nullptr,
      gate_w2, gate_b2, gate_w3, gate_b3, sc, nullptr);
  gemm_head<128, 256, 1, 1, 0><<<dim3(16, 16), 256, 0, stream>>>(
      h1, (size_t)512 * 256, exp_w2, exp_b2, exp_g2, exp_bb2, h2,
      nullptr, nullptr, nullptr, nullptr, nullptr, nullptr);
  gemm_head<128, 128, 0, 0, 1><<<dim3(16, 16), 256, 0, stream>>>(
      h2, (size_t)512 * 128, exp_w3, exp_b3, nullptr, nullptr, emb,
      cls_w, cls_b, nullptr, nullptr, lg, conf);

  // ---- routing + outputs ----
  routing_k<<<1, 512, 0, stream>>>(sc, conf, lg, (float*)d_out);
}

// Round 12
// 687.948 us; speedup vs baseline: 1.0032x; 1.0032x over previous
//
#include <hip/hip_runtime.h>

// ============================================================================
// ImprovedMoE R30 = R29 + hi-only activations for the LAST TWO convs:
// conv5/conv6 read only the fp16 hi plane (ALO=0: one MFMA per tap per n
// instead of two, single-plane sA staging -> half the LDS/A-traffic/MFMA),
// and their producers skip lo-plane writes (conv4/conv5 OLO=0, -12.6MB HBM).
// Error analysis: dropping Al adds <=2^-11|a| per element, summing
// incoherently over 1152-2304-term dots (~5e-4 rel on conv5/6 out, ~1e-3 on
// feats; LN keeps it relative) -> predicted absmax ~0.01-0.015 < 0.0323.
// conv1/2/3 keep full hi+lo precision. R29 head fusion retained.
// ============================================================================

typedef _Float16 h16;
typedef _Float16 half8 __attribute__((ext_vector_type(8)));
typedef float f32x16 __attribute__((ext_vector_type(16)));

__device__ __forceinline__ void split2f(float x, h16& hh, h16& ll) {
  h16 a = (h16)x;
  hh = a;
  ll = (h16)(x - (float)a);
}

__device__ __forceinline__ void dma_b16(const h16* g, h16* l) {
  __builtin_amdgcn_global_load_lds(
      (const __attribute__((address_space(1))) void*)g,
      (__attribute__((address_space(3))) void*)l, 16, 0, 0);
}

// ---- fused prep: zero pads + conv1 wt transpose + conv2..6 weight split ----
__global__ void prep_all_k(const float* __restrict__ cw1, const float* __restrict__ cw2,
                           const float* __restrict__ cw3, const float* __restrict__ cw4,
                           const float* __restrict__ cw5, const float* __restrict__ cw6,
                           float* __restrict__ wt1t, h16* __restrict__ wh,
                           h16* p0, h16* p1, h16* p2, h16* p3) {
  int idx = blockIdx.x * 256 + threadIdx.x;
  if (idx < 64) {
    h16* p = (idx < 16) ? p0 : (idx < 32) ? p1 : (idx < 48) ? p2 : p3;
    p[idx & 15] = (h16)0.f;
    return;
  }
  idx -= 64;
  if (idx < 1728) {
    int co = idx % 64, r = idx / 64;
    wt1t[idx] = cw1[(size_t)co * 27 + r];
    return;
  }
  idx -= 1728;
  const float* w; int CIN, COUT; size_t off;
  if (idx < 36864)        { w = cw2; CIN = 64;  COUT = 64;  off = 0; }
  else if (idx < 110592)  { w = cw3; CIN = 64;  COUT = 128; off = 36864;  idx -= 36864; }
  else if (idx < 258048)  { w = cw4; CIN = 128; COUT = 128; off = 110592; idx -= 110592; }
  else if (idx < 552960)  { w = cw5; CIN = 128; COUT = 256; off = 258048; idx -= 258048; }
  else if (idx < 1142784) { w = cw6; CIN = 256; COUT = 256; off = 552960; idx -= 552960; }
  else return;
  int KCOB = COUT >> 6;
  int lidx = idx;
  int c8   = idx & 7;
  int t    = idx >> 3;
  int co64 = t & 63;  t >>= 6;
  int half = t & 1;   t >>= 1;
  int cob  = t % KCOB; t /= KCOB;
  int tap  = t % 9;
  int ck   = t / 9;
  int ci = ck * 16 + half * 8 + c8;
  int co = cob * 64 + co64;
  float v = w[((size_t)co * CIN + ci) * 9 + tap];
  wh[off + lidx] = (h16)v;
}

// ---- conv1: 3->64, 32x32, fp32 vector; outputs blocked hi/lo planes (+16) ----
__global__ __launch_bounds__(256) void conv1_k(
    const float* __restrict__ x, const float* __restrict__ wt,
    const float* __restrict__ cb, const float* __restrict__ bns,
    const float* __restrict__ bnb, h16* __restrict__ oh, h16* __restrict__ ol)
{
  __shared__ float sx[3 * 34 * 34];
  const int tid = threadIdx.x;
  const int img = blockIdx.x;
  for (int idx = tid; idx < 3 * 34 * 34; idx += 256) {
    int xx = idx % 34;
    int t  = idx / 34;
    int rr = t % 34;
    int c  = t / 34;
    int gr = rr - 1, gx = xx - 1;
    float v = 0.f;
    if (gr >= 0 && gr < 32 && gx >= 0 && gx < 32)
      v = x[((size_t)(img * 3 + c) * 32 + gr) * 32 + gx];
    sx[(c * 34 + rr) * 34 + xx] = v;
  }
  __syncthreads();
#pragma unroll 1
  for (int k = 0; k < 4; ++k) {
    int px = k * 256 + tid;
    int yy = px >> 5, xx = px & 31;
    float in27[27];
#pragma unroll
    for (int c = 0; c < 3; ++c)
#pragma unroll
      for (int dy = 0; dy < 3; ++dy)
#pragma unroll
        for (int dx = 0; dx < 3; ++dx)
          in27[c * 9 + dy * 3 + dx] = sx[(c * 34 + yy + dy) * 34 + xx + dx];
#pragma unroll 1
    for (int cbk = 0; cbk < 4; ++cbk) {
      h16 hb[16], lb[16];
#pragma unroll
      for (int j = 0; j < 16; ++j) {
        int co = cbk * 16 + j;
        float acc = 0.f;
#pragma unroll
        for (int t = 0; t < 27; ++t) acc = fmaf(in27[t], wt[t * 64 + co], acc);
        float s = bns[co];
        float yv = fmaxf(fmaf(acc + cb[co], s, bnb[co]), 0.f);
        split2f(yv, hb[j], lb[j]);
      }
      size_t o = 16 + ((size_t)(img * 4 + cbk) * 1024 + px) * 16;
      *(half8*)&oh[o]     = *(half8*)&hb[0];
      *(half8*)&oh[o + 8] = *(half8*)&hb[8];
      *(half8*)&ol[o]     = *(half8*)&lb[0];
      *(half8*)&ol[o + 8] = *(half8*)&lb[8];
    }
  }
}

// ---------------------------------------------------------------------------
// MFMA conv: 3x3 SAME, tap-decomposed implicit GEMM.
// ALO=1: D = (Ah+Al)*Bh (two MFMAs/tap/n).  ALO=0: D = Ah*Bh (one).
// OLO=1: write Oh+Ol.  OLO=0: write Oh only (consumer is ALO=0).
// HSPLIT staging (conflict-free), clamped halos, BREG, DBUF/KU as R27.
// ---------------------------------------------------------------------------
template<int H, int W, int CIN, int COUT, int MT, int POOL, int OCC, int DBUF,
         int BREG, int KU, int ALO, int OLO>
__global__ __launch_bounds__(256, OCC) void conv_mfma(
    const h16* __restrict__ Ah, const h16* __restrict__ Al,
    const h16* __restrict__ Wh,
    const float* __restrict__ cb, const float* __restrict__ bns,
    const float* __restrict__ bnb,
    h16* __restrict__ Oh, h16* __restrict__ Ol, float* __restrict__ feats)
{
  constexpr int TPI  = (H * W) / 32;
  constexpr int RPT  = 32 / W;
  constexpr int IPB  = (4 * MT * 32 >= H * W) ? (4 * MT * 32) / (H * W) : 1;
  constexpr int KC   = CIN / 16;
  constexpr int HW   = H * W;
  constexpr int KCO  = COUT / 16;
  constexpr int KCOB = COUT / 64;
  constexpr int LOGW = (W == 32) ? 5 : (W == 16) ? 4 : 3;
  constexpr int ROWS_COV = (4 * MT * 32) / (W * IPB);   // rows covered / image
  constexpr int ROFF  = (ROWS_COV < H) ? 1 : 0;          // staged halo rows
  constexpr int SROWS = ROWS_COV + 2 * ROFF;
  constexpr int ASZ = IPB * SROWS * W * 16;              // h16 per plane
  constexpr int ACH = ASZ / 8;                           // 16B chunks/plane
  constexpr int ACH2 = ACH / 2;                          // chunks/(plane,hs)
  constexpr int NPL = ALO ? 2 : 1;                       // staged A planes
  constexpr int NBUF = DBUF ? 2 : 1;
  constexpr int TCH  = BREG ? (KU * NPL * ACH) : (1152 + NPL * ACH);
  constexpr int NI   = (TCH + 255) / 256;
  constexpr int SBH  = 9 * 2 * 64 * 8;                   // h16 per sB buffer
  constexpr int SBSZ = BREG ? 8 : (NBUF * SBH);

  __shared__ h16 sB[SBSZ];
  __shared__ h16 sA[NBUF][KU][NPL][ASZ + 16];            // +16 = zero sentinel

  const int tid  = threadIdx.x;
  const int lane = tid & 63;
  const int wave = tid >> 6;
  const int half = lane >> 5;
  const int col  = lane & 31;
  const int cob  = blockIdx.z;
  const int co0  = cob * 64;
  const int r0img = blockIdx.y * ROWS_COV;

  auto stageA = [&](int ck, int nb, int ku, int cc2) {
    int pl = cc2 / ACH;                  // 0..NPL-1
    int cc = cc2 - pl * ACH;             // linear LDS dest chunk (required)
    // HSPLIT [hs][px] sub-planes; ACH2 % 64 == 0 -> hs wave-uniform.
    int hs  = cc / ACH2;
    int px  = cc - hs * ACH2;
    int iL  = px / (SROWS * W);
    int rem = px - iL * (SROWS * W);
    int rs  = rem / W;
    int pxx = rem - rs * W;
    int grow = r0img + rs - ROFF;
    if constexpr (ROFF == 1) {
      // CLAMP (not skip): all lanes stay active -> no exec divergence.
      grow = grow < 0 ? 0 : (grow >= H ? H - 1 : grow);
    }
    const h16* gp = pl ? Al : Ah;
    int srcA = 16 + (((blockIdx.x * IPB + iL) * KC + ck) * HW + grow * W + pxx) * 16 + hs * 8;
    dma_b16(gp + srcA, &sA[nb][ku][pl][cc * 8]);
  };

  auto STAGE = [&](int ck0, int nb) {
#pragma unroll
    for (int i = 0; i < NI; ++i) {
      int id = tid + i * 256;
      if constexpr (BREG) {
        if (id < TCH) {
          int ku = id / (NPL * ACH);
          stageA(ck0 + ku, nb, ku, id - ku * NPL * ACH);
        }
      } else {
        if (id < 1152) {
          int src = ((ck0 * 9 + (id >> 7)) * KCOB + cob) * 1024 + (id & 127) * 8;
          dma_b16(Wh + src, &sB[nb * SBH + id * 8]);
        } else if (id < TCH) {
          stageA(ck0, nb, 0, id - 1152);
        }
      }
    }
  };

  int scc[MT], ty[MT], tx[MT], img_t[MT], rw0[MT];
#pragma unroll
  for (int t = 0; t < MT; ++t) {
    int gt   = blockIdx.y * (4 * MT) + wave * MT + t;
    int imgL = (gt / TPI) % IPB;
    int img  = blockIdx.x * IPB + gt / TPI;
    int row0 = (gt % TPI) * RPT;
    int y = row0 + (col >> LOGW);
    int x = col & (W - 1);
    img_t[t] = img; rw0[t] = row0; ty[t] = y; tx[t] = x;
    scc[t] = half * ACH2 + (imgL * SROWS + (y - r0img + ROFF)) * W + x;  // chunk
  }

  f32x16 acc[MT][2];
#pragma unroll
  for (int t = 0; t < MT; ++t)
#pragma unroll
    for (int n = 0; n < 2; ++n)
#pragma unroll
      for (int i = 0; i < 16; ++i) acc[t][n][i] = 0.f;

  // zero the halo sentinels + stage stage-0 into buffer 0
  if (tid < NBUF * KU * NPL * 16) {
    int wsl = tid >> 4;                  // [nb][ku][pl] slot
    int pl = wsl % NPL;
    int kq = (wsl / NPL) % KU;
    int nb = wsl / (NPL * KU);
    sA[nb][kq][pl][ASZ + (tid & 15)] = (h16)0.f;
  }
  STAGE(0, 0);
  __syncthreads();

  const int zoff = ASZ + half * 8;   // sentinel (h16 offset)

  int buf = 0;
#pragma unroll 1
  for (int cc = 0; cc < KC; cc += KU) {
    if constexpr (DBUF) {
      if (cc + KU < KC) STAGE(cc + KU, buf ^ 1);   // lands under the tap loops
    }
#pragma unroll
    for (int ku = 0; ku < KU; ++ku) {
      const int ck = cc + ku;
      const h16* bB = &sB[BREG ? 0 : (buf * SBH)];
      const h16* aH = &sA[buf][ku][0][0];
      const h16* aL = ALO ? &sA[buf][ku][NPL - 1][0] : nullptr;
      const h16* bG = Wh + ((size_t)ck * 9 * KCOB + cob) * 1024 + half * 512;

#pragma unroll
      for (int tap = 0; tap < 9; ++tap) {
        const int dy = tap / 3 - 1, dx = tap % 3 - 1;
        const int dsh = dy * W + dx;          // pixel (=chunk) delta
        half8 bh[2];
        if constexpr (BREG) {
          const h16* bt = bG + (size_t)tap * KCOB * 1024;
          bh[0] = *(const half8*)&bt[col * 8];
          bh[1] = *(const half8*)&bt[(32 + col) * 8];
        } else {
#pragma unroll
          for (int n = 0; n < 2; ++n)
            bh[n] = *(const half8*)&bB[((tap * 2 + half) * 64 + n * 32 + col) * 8];
        }
        half8 ah[MT], al[MT];
#pragma unroll
        for (int t = 0; t < MT; ++t) {
          bool v = ((unsigned)(ty[t] + dy) < (unsigned)H) &&
                   ((unsigned)(tx[t] + dx) < (unsigned)W);
          int po = v ? ((scc[t] + dsh) * 8) : zoff;
          ah[t] = *(const half8*)(aH + po);
          if constexpr (ALO) al[t] = *(const half8*)(aL + po);
        }
#pragma unroll
        for (int t = 0; t < MT; ++t)
#pragma unroll
          for (int n = 0; n < 2; ++n) {
            acc[t][n] = __builtin_amdgcn_mfma_f32_32x32x16_f16(ah[t], bh[n], acc[t][n], 0, 0, 0);
            if constexpr (ALO)
              acc[t][n] = __builtin_amdgcn_mfma_f32_32x32x16_f16(al[t], bh[n], acc[t][n], 0, 0, 0);
          }
      }
    }

    if constexpr (DBUF) {
      __syncthreads();   // drains the DMA (vmcnt) + orders buffer swap
      buf ^= 1;
    } else {
      __syncthreads();   // all waves done reading sA/sB
      if (cc + KU < KC) {
        STAGE(cc + KU, 0);
        __syncthreads(); // drains DMA -> buffers hold next stage
      }
    }
  }

#pragma unroll
  for (int n = 0; n < 2; ++n) {
    const int co = co0 + n * 32 + col;
    const float es = bns[co];
    const float eb = fmaf(cb[co], es, bnb[co]);
    const int cko = co >> 4, c16 = co & 15;

    if constexpr (POOL == 0) {
#pragma unroll
      for (int t = 0; t < MT; ++t) {
#pragma unroll
        for (int r = 0; r < 16; ++r) {
          float v = fmaxf(fmaf(acc[t][n][r], es, eb), 0.f);
          int m = (r & 3) + 4 * half + 8 * (r >> 2);
          int y = rw0[t] + (m >> LOGW);
          int x = m & (W - 1);
          size_t oi = 16 + ((size_t)(img_t[t] * KCO + cko) * HW + y * W + x) * 16 + c16;
          h16 hh, ll; split2f(v, hh, ll);
          Oh[oi] = hh;
          if constexpr (OLO) Ol[oi] = ll;
        }
      }
    } else if constexpr (POOL == 1 && RPT == 1) {
      constexpr int HWq = (H / 2) * (W / 2);
#pragma unroll
      for (int tp = 0; tp < MT / 2; ++tp) {
        const int t0 = 2 * tp, t1 = 2 * tp + 1;
        const int yq = rw0[t0] >> 1;
#pragma unroll
        for (int r = 0; r < 16; r += 2) {
          float v00 = fmaxf(fmaf(acc[t0][n][r],     es, eb), 0.f);
          float v01 = fmaxf(fmaf(acc[t0][n][r + 1], es, eb), 0.f);
          float v10 = fmaxf(fmaf(acc[t1][n][r],     es, eb), 0.f);
          float v11 = fmaxf(fmaf(acc[t1][n][r + 1], es, eb), 0.f);
          float mv = fmaxf(fmaxf(v00, v01), fmaxf(v10, v11));
          int xq = ((r & 3) >> 1) + 2 * half + 4 * (r >> 2);
          size_t oi = 16 + ((size_t)(img_t[t0] * KCO + cko) * HWq + yq * (W / 2) + xq) * 16 + c16;
          h16 hh, ll; split2f(mv, hh, ll);
          Oh[oi] = hh;
          if constexpr (OLO) Ol[oi] = ll;
        }
      }
    } else if constexpr (POOL == 1) {
      constexpr int HWq = (H / 2) * (W / 2);
#pragma unroll
      for (int t = 0; t < MT; ++t) {
        const int yq = rw0[t] >> 1;
#pragma unroll
        for (int r = 0; r < 8; r += 2) {
          float v00 = fmaxf(fmaf(acc[t][n][r],     es, eb), 0.f);
          float v01 = fmaxf(fmaf(acc[t][n][r + 1], es, eb), 0.f);
          float v10 = fmaxf(fmaf(acc[t][n][r + 8], es, eb), 0.f);
          float v11 = fmaxf(fmaf(acc[t][n][r + 9], es, eb), 0.f);
          float mv = fmaxf(fmaxf(v00, v01), fmaxf(v10, v11));
          int xq = ((r & 3) >> 1) + 2 * half + 4 * (r >> 2);
          size_t oi = 16 + ((size_t)(img_t[t] * KCO + cko) * HWq + yq * (W / 2) + xq) * 16 + c16;
          h16 hh, ll; split2f(mv, hh, ll);
          Oh[oi] = hh;
          if constexpr (OLO) Ol[oi] = ll;
        }
      }
    } else if constexpr (POOL == 2 && MT == 1) {
      // reuse sA[0] as the reduction scratch (all reads drained by last barrier)
      float* sRd = (float*)&sA[0][0][0][0];
      float s = 0.f;
#pragma unroll
      for (int r = 0; r < 16; ++r)
        s += fmaxf(fmaf(acc[0][n][r], es, eb), 0.f);
      s += __shfl_xor(s, 32, 64);
      if (half == 0) sRd[wave * 64 + n * 32 + col] = s;
    } else if constexpr (POOL == 2) {
      float s = 0.f;
#pragma unroll
      for (int t = 0; t < MT; ++t)
#pragma unroll
        for (int r = 0; r < 16; ++r)
          s += fmaxf(fmaf(acc[t][n][r], es, eb), 0.f);
      s += __shfl_xor(s, 32, 64);
      if (half == 0) feats[(size_t)img_t[0] * 256 + co] = s * (1.f / 64.f);
    }
  }

  if constexpr (POOL == 2 && MT == 1) {
    float* sRd = (float*)&sA[0][0][0][0];
    __syncthreads();
    if (tid < 128) {
      int li = tid >> 6, co_l = tid & 63;
      float s = sRd[(li * 2) * 64 + co_l] + sRd[(li * 2 + 1) * 64 + co_l];
      feats[(size_t)(blockIdx.x * 2 + li) * 256 + co0 + co_l] = s * (1.f / 64.f);
    }
  }
}

// ---------------------------------------------------------------------------
// Batched head GEMM: 32 batch rows/block, one expert per blockIdx.y.
// HEAD=0: plain (store out). HEAD=1: + cls logits/softmax/entropy fused
// (out store dropped; writes o1=logits_e, o2=conf). HEAD=2: + gate2/gate3
// fused (out store dropped; writes o1=scores).
// ---------------------------------------------------------------------------
template<int O, int K, int LN, int RELU, int HEAD>
__global__ __launch_bounds__(256, 4) void gemm_head(
    const float* __restrict__ A, size_t aStrideE,
    const float* __restrict__ Wm, const float* __restrict__ bias,
    const float* __restrict__ g, const float* __restrict__ bb,
    float* __restrict__ out,
    const float* __restrict__ xw1, const float* __restrict__ xb1,
    const float* __restrict__ xw2, const float* __restrict__ xb2,
    float* __restrict__ o1, float* __restrict__ o2)
{
  constexpr int KC  = (O >= 256) ? 32 : 64;
  constexpr int WST = O + 4;
  constexpr int TO  = O / 16;
  __shared__ float sA[KC * 36];
  __shared__ float sW[KC * WST];
  __shared__ float mArr[32], rArr[32];

  const int tid  = threadIdx.x;
  const int lane = tid & 63;
  const int wave = tid >> 6;
  const int e    = blockIdx.y;
  const int b0g  = blockIdx.x * 32;
  const int bl   = (lane & 15) * 2;
  const int ol   = wave * (O / 4) + (lane >> 4) * TO;

  const float* Ae = A + (size_t)e * aStrideE;
  const float* We = Wm + (size_t)e * O * K;

  float acc[2][TO];
#pragma unroll
  for (int i = 0; i < 2; ++i)
#pragma unroll
    for (int j = 0; j < TO; ++j) acc[i][j] = 0.f;

  for (int k0 = 0; k0 < K; k0 += KC) {
    for (int idx = tid; idx < 32 * KC; idx += 256) {
      int kk = idx % KC, bb_ = idx / KC;
      sA[kk * 36 + bb_] = Ae[(size_t)(b0g + bb_) * K + k0 + kk];
    }
    for (int idx = tid; idx < O * KC; idx += 256) {
      int kk = idx % KC, oo = idx / KC;
      sW[kk * WST + oo] = We[(size_t)oo * K + k0 + kk];
    }
    __syncthreads();
#pragma unroll 4
    for (int kk = 0; kk < KC; ++kk) {
      float2 av = *(const float2*)&sA[kk * 36 + bl];
      float a2[2] = {av.x, av.y};
#pragma unroll
      for (int j4 = 0; j4 < TO; j4 += 4) {
        float4 wv = *(const float4*)&sW[kk * WST + ol + j4];
        float w4[4] = {wv.x, wv.y, wv.z, wv.w};
#pragma unroll
        for (int i = 0; i < 2; ++i)
#pragma unroll
          for (int jj = 0; jj < 4; ++jj)
            acc[i][j4 + jj] = fmaf(a2[i], w4[jj], acc[i][j4 + jj]);
      }
    }
    __syncthreads();
  }

  const float* bi = bias + (size_t)e * O;
#pragma unroll
  for (int i = 0; i < 2; ++i)
#pragma unroll
    for (int j = 0; j < TO; ++j) acc[i][j] += bi[ol + j];

  if constexpr (LN) {
    float* redS = sA;
    float* redQ = sA + 512;
    const int grp = wave * 4 + (lane >> 4);
#pragma unroll
    for (int i = 0; i < 2; ++i) {
      float s = 0.f, q = 0.f;
#pragma unroll
      for (int j = 0; j < TO; ++j) { s += acc[i][j]; q += acc[i][j] * acc[i][j]; }
      redS[(bl + i) * 16 + grp] = s;
      redQ[(bl + i) * 16 + grp] = q;
    }
    __syncthreads();
    if (tid < 32) {
      float s = 0.f, q = 0.f;
#pragma unroll
      for (int gi = 0; gi < 16; ++gi) { s += redS[tid * 16 + gi]; q += redQ[tid * 16 + gi]; }
      float mean = s * (1.f / O);
      float var  = q * (1.f / O) - mean * mean;
      mArr[tid] = mean;
      rArr[tid] = rsqrtf(var + 1e-5f);
    }
    __syncthreads();
    const float* gp  = g + (size_t)e * O;
    const float* bbp = bb + (size_t)e * O;
#pragma unroll
    for (int i = 0; i < 2; ++i) {
      float mean = mArr[bl + i], rstd = rArr[bl + i];
#pragma unroll
      for (int j = 0; j < TO; ++j)
        acc[i][j] = (acc[i][j] - mean) * rstd * gp[ol + j] + bbp[ol + j];
    }
  }
  if constexpr (RELU) {
#pragma unroll
    for (int i = 0; i < 2; ++i)
#pragma unroll
      for (int j = 0; j < TO; ++j) acc[i][j] = fmaxf(acc[i][j], 0.f);
  }

  if constexpr (HEAD == 0) {
#pragma unroll
    for (int i = 0; i < 2; ++i) {
      float* op = out + ((size_t)e * 512 + b0g + bl + i) * O + ol;
#pragma unroll
      for (int j4 = 0; j4 < TO; j4 += 4)
        *(float4*)(op + j4) = make_float4(acc[i][j4], acc[i][j4 + 1], acc[i][j4 + 2], acc[i][j4 + 3]);
    }
  } else if constexpr (HEAD == 1) {
    // ---- fused cls: logits (lg), softmax entropy -> conf. emb not stored.
    float* et = sW;                      // 32 x WST tile (sW is free here)
    __syncthreads();                     // all sW reads of the K loop done
#pragma unroll
    for (int i = 0; i < 2; ++i)
#pragma unroll
      for (int j = 0; j < TO; ++j) et[(bl + i) * WST + ol + j] = acc[i][j];
    __syncthreads();
    // 320 work items (32 b x 10 o) on 256 threads: block-stride loop.
    for (int idx = tid; idx < 320; idx += 256) {
      int b = idx / 10, o = idx - (idx / 10) * 10;
      const float* wp = xw1 + ((size_t)e * 10 + o) * O;
      const float* er = et + b * WST;
      float s = 0.f;
      for (int c = 0; c < O; ++c) s = fmaf(er[c], wp[c], s);
      s += xb1[e * 10 + o];
      o1[((size_t)(b0g + b) * 16 + e) * 10 + o] = s;
      sA[b * 10 + o] = s;
    }
    __syncthreads();
    if (tid < 32) {
      int b = tid;
      float l0[10];
#pragma unroll
      for (int o = 0; o < 10; ++o) l0[o] = sA[b * 10 + o];
      float m = l0[0];
#pragma unroll
      for (int o = 1; o < 10; ++o) m = fmaxf(m, l0[o]);
      float p0[10], sum = 0.f;
#pragma unroll
      for (int o = 0; o < 10; ++o) { p0[o] = expf(l0[o] - m); sum += p0[o]; }
      float inv = 1.f / sum, ent = 0.f;
#pragma unroll
      for (int o = 0; o < 10; ++o) { float pp = p0[o] * inv; ent -= pp * logf(pp + 1e-12f); }
      o2[(size_t)(b0g + b) * 16 + e] = -ent;
    }
  } else {
    // ---- fused gate2 (1024 parallel 64-dots) + gate3 -> scores. g1 not stored.
    float* gt = sW;                      // 32 x WST tile
    __syncthreads();
#pragma unroll
    for (int i = 0; i < 2; ++i)
#pragma unroll
      for (int j = 0; j < TO; ++j) gt[(bl + i) * WST + ol + j] = acc[i][j];
    __syncthreads();
#pragma unroll
    for (int p = 0; p < 4; ++p) {
      int idx = tid + p * 256;           // 1024 (b, o2) pairs
      int b = idx >> 5, o2i = idx & 31;
      const float* wr = xw1 + ((size_t)e * 32 + o2i) * 64;
      const float* gr = gt + b * WST;
      float s = 0.f;
      for (int c = 0; c < 64; ++c) s = fmaf(gr[c], wr[c], s);
      sA[b * 36 + o2i] = fmaxf(s + xb1[e * 32 + o2i], 0.f);
    }
    __syncthreads();
    if (tid < 32) {
      int b = tid;
      const float* w3p = xw2 + e * 32;
      float s = 0.f;
#pragma unroll
      for (int oo = 0; oo < 32; ++oo) s = fmaf(sA[b * 36 + oo], w3p[oo], s);
      o1[(size_t)(b0g + b) * 16 + e] = s + xb2[e];
    }
  }
}

__global__ void routing_k(const float* __restrict__ scores, const float* __restrict__ conf,
                          const float* __restrict__ logits_e, float* __restrict__ out)
{
  __shared__ int t2[512];
  __shared__ int chs[512];
  const int tid = threadIdx.x;

  if (tid < 512) {
    int b = tid;
    float v0 = -3.4e38f, v1 = -3.4e38f;
    int i0 = 0, i1 = 0;
#pragma unroll
    for (int e = 0; e < 16; ++e) {
      float s = scores[b * 16 + e];
      float c = conf[b * 16 + e];
      float v = 0.7f * s + 0.3f * c - 0.125f;
      out[5120 + b * 16 + e] = v;
      if (v > v0) { v1 = v0; i1 = i0; v0 = v; i0 = e; }
      else if (v > v1) { v1 = v; i1 = e; }
    }
    t2[b] = i0 | (i1 << 8);
  }
  __syncthreads();

  if (tid < 64) {
    int lane = tid;
    int cnt = 0;
    int pk[8];
#pragma unroll
    for (int k = 0; k < 8; ++k) pk[k] = t2[k * 64 + lane];
#pragma unroll 1
    for (int k = 0; k < 8; ++k) {
      for (int j = 0; j < 64; ++j) {
        int pair = __shfl(pk[k], j, 64);
        int i0 = pair & 0xff, i1 = (pair >> 8) & 0xff;
        int c0 = __shfl(cnt, i0, 64);
        int c1 = __shfl(cnt, i1, 64);
        int ch = (c0 < 64) ? i0 : ((c1 < 64) ? i1 : ((c0 <= c1) ? i0 : i1));
        cnt += (lane == ch) ? 1 : 0;
        if (lane == 0) chs[k * 64 + j] = ch;
      }
    }
  }
  __syncthreads();

  if (tid < 512) {
    int b = tid;
    int ch = chs[b];
#pragma unroll
    for (int e = 0; e < 16; ++e)
      out[13312 + b * 16 + e] = (e == ch) ? 1.0f : 0.0f;
#pragma unroll
    for (int o = 0; o < 10; ++o)
      out[b * 10 + o] = logits_e[((size_t)b * 16 + ch) * 10 + o];
  }
}

// ============================================================================
extern "C" void kernel_launch(void* const* d_in, const int* in_sizes, int n_in,
                              void* d_out, int out_size, void* d_ws, size_t ws_size,
                              hipStream_t stream) {
  (void)in_sizes; (void)n_in; (void)out_size; (void)ws_size;

  const float* x = (const float*)d_in[0];
  const float *cw[6], *cbv[6], *bsv[6], *bbv[6];
  for (int i = 0; i < 6; ++i) {
    cw[i]  = (const float*)d_in[1 + 4 * i];
    cbv[i] = (const float*)d_in[2 + 4 * i];
    bsv[i] = (const float*)d_in[3 + 4 * i];
    bbv[i] = (const float*)d_in[4 + 4 * i];
  }
  const float* gate_w1  = (const float*)d_in[25];
  const float* gate_b1  = (const float*)d_in[26];
  const float* gate_g1  = (const float*)d_in[27];
  const float* gate_bb1 = (const float*)d_in[28];
  const float* gate_w2  = (const float*)d_in[29];
  const float* gate_b2  = (const float*)d_in[30];
  const float* gate_w3  = (const float*)d_in[31];
  const float* gate_b3  = (const float*)d_in[32];
  const float* exp_w1   = (const float*)d_in[33];
  const float* exp_b1   = (const float*)d_in[34];
  const float* exp_g1   = (const float*)d_in[35];
  const float* exp_bb1  = (const float*)d_in[36];
  const float* exp_w2   = (const float*)d_in[37];
  const float* exp_b2   = (const float*)d_in[38];
  const float* exp_g2   = (const float*)d_in[39];
  const float* exp_bb2  = (const float*)d_in[40];
  const float* exp_w3   = (const float*)d_in[41];
  const float* exp_b3   = (const float*)d_in[42];
  const float* cls_w    = (const float*)d_in[43];
  const float* cls_b    = (const float*)d_in[44];

  char* wsb = (char*)d_ws;
  const size_t off_wt1t = 0;
  const size_t off_whi  = 6912;
  const size_t off_Phi  = 4578048;
  const size_t off_Plo  = 71687168;
  const size_t off_Qhi  = 138796288;
  const size_t off_Qlo  = 155573760;
  const size_t off_feats= 172351232;
  const size_t off_h1   = 138796288 + 512;
  const size_t off_h2   = off_h1 + 8388608;
  const size_t off_emb  = off_h2 + 4194304;
  const size_t off_g1   = off_emb + 4194304;
  const size_t off_lg   = off_g1 + 2097152;
  const size_t off_conf = off_lg + 327680;
  const size_t off_sc   = off_conf + 32768;

  float* wt1t = (float*)(wsb + off_wt1t);
  h16* whi = (h16*)(wsb + off_whi);
  h16* Phi = (h16*)(wsb + off_Phi);
  h16* Plo = (h16*)(wsb + off_Plo);
  h16* Qhi = (h16*)(wsb + off_Qhi);
  h16* Qlo = (h16*)(wsb + off_Qlo);
  float* feats = (float*)(wsb + off_feats);
  float* h1 = (float*)(wsb + off_h1);
  float* h2 = (float*)(wsb + off_h2);
  float* emb = (float*)(wsb + off_emb);
  float* lg = (float*)(wsb + off_lg);
  float* conf = (float*)(wsb + off_conf);
  float* sc = (float*)(wsb + off_sc);

  const size_t wo2 = 0;
  const size_t wo3 = 36864;
  const size_t wo4 = 110592;
  const size_t wo5 = 258048;
  const size_t wo6 = 552960;

  // ---- fused prep (pads + wt1 transpose + all weight splits) ----
  prep_all_k<<<4471, 256, 0, stream>>>(cw[0], cw[1], cw[2], cw[3], cw[4], cw[5],
                                       wt1t, whi, Phi, Plo, Qhi, Qlo);

  // ---- trunk ----
  conv1_k<<<512, 256, 0, stream>>>(x, wt1t, cbv[0], bsv[0], bbv[0], Phi, Plo);
  // <H, W, CIN, COUT, MT, POOL, OCC, DBUF, BREG, KU, ALO, OLO>
  conv_mfma<32, 32, 64, 64, 2, 1, 3, 1, 1, 1, 1, 1><<<dim3(512, 4, 1), 256, 0, stream>>>(
      Phi, Plo, whi + wo2, cbv[1], bsv[1], bbv[1], Qhi, Qlo, nullptr);
  conv_mfma<16, 16, 64, 128, 2, 0, 3, 1, 1, 1, 1, 1><<<dim3(512, 1, 2), 256, 0, stream>>>(
      Qhi, Qlo, whi + wo3, cbv[2], bsv[2], bbv[2], Phi, Plo, nullptr);
  // conv4: consumer (conv5) is hi-only -> skip Ql writes (OLO=0)
  conv_mfma<16, 16, 128, 128, 2, 1, 3, 1, 1, 1, 1, 0><<<dim3(512, 1, 2), 256, 0, stream>>>(
      Phi, Plo, whi + wo4, cbv[3], bsv[3], bbv[3], Qhi, Qlo, nullptr);
  // conv5: hi-only A (ALO=0); consumer (conv6) hi-only -> skip Plo (OLO=0)
  conv_mfma<8, 8, 128, 256, 1, 0, 3, 1, 1, 1, 0, 0><<<dim3(256, 1, 4), 256, 0, stream>>>(
      Qhi, Qhi, whi + wo5, cbv[4], bsv[4], bbv[4], Phi, Plo, nullptr);
  // conv6: hi-only A (ALO=0)
  conv_mfma<8, 8, 256, 256, 1, 2, 4, 1, 1, 2, 0, 1><<<dim3(256, 1, 4), 256, 0, stream>>>(
      Phi, Phi, whi + wo6, cbv[5], bsv[5], bbv[5], nullptr, nullptr, feats);

  // ---- experts + gates (heads fused into gate1/exp3 epilogues) ----
  gemm_head<256, 256, 1, 1, 0><<<dim3(16, 16), 256, 0, stream>>>(
      feats, (size_t)0, exp_w1, exp_b1, exp_g1, exp_bb1, h1,
      nullptr, nullptr, nullptr, nullptr, nullptr, nullptr);
  gemm_head<64, 256, 1, 1, 2><<<dim3(16, 16), 256, 0, stream>>>(
      feats, (size_t)0, gate_w1, gate_b1, gate_g1, gate_bb1, nullptr,
      gate_w2, gate_b2, gate_w3, gate_b3, sc, nullptr);
  gemm_head<128, 256, 1, 1, 0><<<dim3(16, 16), 256, 0, stream>>>(
      h1, (size_t)512 * 256, exp_w2, exp_b2, exp_g2, exp_bb2, h2,
      nullptr, nullptr, nullptr, nullptr, nullptr, nullptr);
  gemm_head<128, 128, 0, 0, 1><<<dim3(16, 16), 256, 0, stream>>>(
      h2, (size_t)512 * 128, exp_w3, exp_b3, nullptr, nullptr, emb,
      cls_w, cls_b, nullptr, nullptr, lg, conf);

  // ---- routing + outputs ----
  routing_k<<<1, 512, 0, stream>>>(sc, conf, lg, (float*)d_out);
}

// Round 13
// 597.497 us; speedup vs baseline: 1.1551x; 1.1514x over previous
//
#include <hip/hip_runtime.h>

// ============================================================================
// ImprovedMoE R31 = R30 + hi-only activations for the WHOLE trunk:
// conv2/3/4 now also ALO=0 (one MFMA per tap per n; single-plane sA) and
// OLO=0; conv1 stores only the fp16 hi plane (67MB of lo writes dropped).
// Justification: R30 measured absmax EXACTLY unchanged (0.0078125) after
// making conv5/6 hi-only -> error is dominated by fp16 WEIGHT rounding
// (already single-plane), not activation lo-planes. 4x headroom to the
// 0.0323 threshold; predicted absmax ~0.012-0.02.
// Work: conv2/3/4 MFMA count + A-traffic halve (conv2 was the 74.9us top
// kernel). R29 head fusion + R27 trunk structure retained.
// ============================================================================

typedef _Float16 h16;
typedef _Float16 half8 __attribute__((ext_vector_type(8)));
typedef float f32x16 __attribute__((ext_vector_type(16)));

__device__ __forceinline__ void split2f(float x, h16& hh, h16& ll) {
  h16 a = (h16)x;
  hh = a;
  ll = (h16)(x - (float)a);
}

__device__ __forceinline__ void dma_b16(const h16* g, h16* l) {
  __builtin_amdgcn_global_load_lds(
      (const __attribute__((address_space(1))) void*)g,
      (__attribute__((address_space(3))) void*)l, 16, 0, 0);
}

// ---- fused prep: zero pads + conv1 wt transpose + conv2..6 weight split ----
__global__ void prep_all_k(const float* __restrict__ cw1, const float* __restrict__ cw2,
                           const float* __restrict__ cw3, const float* __restrict__ cw4,
                           const float* __restrict__ cw5, const float* __restrict__ cw6,
                           float* __restrict__ wt1t, h16* __restrict__ wh,
                           h16* p0, h16* p1, h16* p2, h16* p3) {
  int idx = blockIdx.x * 256 + threadIdx.x;
  if (idx < 64) {
    h16* p = (idx < 16) ? p0 : (idx < 32) ? p1 : (idx < 48) ? p2 : p3;
    p[idx & 15] = (h16)0.f;
    return;
  }
  idx -= 64;
  if (idx < 1728) {
    int co = idx % 64, r = idx / 64;
    wt1t[idx] = cw1[(size_t)co * 27 + r];
    return;
  }
  idx -= 1728;
  const float* w; int CIN, COUT; size_t off;
  if (idx < 36864)        { w = cw2; CIN = 64;  COUT = 64;  off = 0; }
  else if (idx < 110592)  { w = cw3; CIN = 64;  COUT = 128; off = 36864;  idx -= 36864; }
  else if (idx < 258048)  { w = cw4; CIN = 128; COUT = 128; off = 110592; idx -= 110592; }
  else if (idx < 552960)  { w = cw5; CIN = 128; COUT = 256; off = 258048; idx -= 258048; }
  else if (idx < 1142784) { w = cw6; CIN = 256; COUT = 256; off = 552960; idx -= 552960; }
  else return;
  int KCOB = COUT >> 6;
  int lidx = idx;
  int c8   = idx & 7;
  int t    = idx >> 3;
  int co64 = t & 63;  t >>= 6;
  int half = t & 1;   t >>= 1;
  int cob  = t % KCOB; t /= KCOB;
  int tap  = t % 9;
  int ck   = t / 9;
  int ci = ck * 16 + half * 8 + c8;
  int co = cob * 64 + co64;
  float v = w[((size_t)co * CIN + ci) * 9 + tap];
  wh[off + lidx] = (h16)v;
}

// ---- conv1: 3->64, 32x32, fp32 vector; hi-plane output only ----
__global__ __launch_bounds__(256) void conv1_k(
    const float* __restrict__ x, const float* __restrict__ wt,
    const float* __restrict__ cb, const float* __restrict__ bns,
    const float* __restrict__ bnb, h16* __restrict__ oh)
{
  __shared__ float sx[3 * 34 * 34];
  const int tid = threadIdx.x;
  const int img = blockIdx.x;
  for (int idx = tid; idx < 3 * 34 * 34; idx += 256) {
    int xx = idx % 34;
    int t  = idx / 34;
    int rr = t % 34;
    int c  = t / 34;
    int gr = rr - 1, gx = xx - 1;
    float v = 0.f;
    if (gr >= 0 && gr < 32 && gx >= 0 && gx < 32)
      v = x[((size_t)(img * 3 + c) * 32 + gr) * 32 + gx];
    sx[(c * 34 + rr) * 34 + xx] = v;
  }
  __syncthreads();
#pragma unroll 1
  for (int k = 0; k < 4; ++k) {
    int px = k * 256 + tid;
    int yy = px >> 5, xx = px & 31;
    float in27[27];
#pragma unroll
    for (int c = 0; c < 3; ++c)
#pragma unroll
      for (int dy = 0; dy < 3; ++dy)
#pragma unroll
        for (int dx = 0; dx < 3; ++dx)
          in27[c * 9 + dy * 3 + dx] = sx[(c * 34 + yy + dy) * 34 + xx + dx];
#pragma unroll 1
    for (int cbk = 0; cbk < 4; ++cbk) {
      h16 hb[16];
#pragma unroll
      for (int j = 0; j < 16; ++j) {
        int co = cbk * 16 + j;
        float acc = 0.f;
#pragma unroll
        for (int t = 0; t < 27; ++t) acc = fmaf(in27[t], wt[t * 64 + co], acc);
        float s = bns[co];
        float yv = fmaxf(fmaf(acc + cb[co], s, bnb[co]), 0.f);
        hb[j] = (h16)yv;
      }
      size_t o = 16 + ((size_t)(img * 4 + cbk) * 1024 + px) * 16;
      *(half8*)&oh[o]     = *(half8*)&hb[0];
      *(half8*)&oh[o + 8] = *(half8*)&hb[8];
    }
  }
}

// ---------------------------------------------------------------------------
// MFMA conv: 3x3 SAME, tap-decomposed implicit GEMM.
// ALO=1: D = (Ah+Al)*Bh (two MFMAs/tap/n).  ALO=0: D = Ah*Bh (one).
// OLO=1: write Oh+Ol.  OLO=0: write Oh only (consumer is ALO=0).
// HSPLIT staging (conflict-free), clamped halos, BREG, DBUF/KU as R27.
// ---------------------------------------------------------------------------
template<int H, int W, int CIN, int COUT, int MT, int POOL, int OCC, int DBUF,
         int BREG, int KU, int ALO, int OLO>
__global__ __launch_bounds__(256, OCC) void conv_mfma(
    const h16* __restrict__ Ah, const h16* __restrict__ Al,
    const h16* __restrict__ Wh,
    const float* __restrict__ cb, const float* __restrict__ bns,
    const float* __restrict__ bnb,
    h16* __restrict__ Oh, h16* __restrict__ Ol, float* __restrict__ feats)
{
  constexpr int TPI  = (H * W) / 32;
  constexpr int RPT  = 32 / W;
  constexpr int IPB  = (4 * MT * 32 >= H * W) ? (4 * MT * 32) / (H * W) : 1;
  constexpr int KC   = CIN / 16;
  constexpr int HW   = H * W;
  constexpr int KCO  = COUT / 16;
  constexpr int KCOB = COUT / 64;
  constexpr int LOGW = (W == 32) ? 5 : (W == 16) ? 4 : 3;
  constexpr int ROWS_COV = (4 * MT * 32) / (W * IPB);   // rows covered / image
  constexpr int ROFF  = (ROWS_COV < H) ? 1 : 0;          // staged halo rows
  constexpr int SROWS = ROWS_COV + 2 * ROFF;
  constexpr int ASZ = IPB * SROWS * W * 16;              // h16 per plane
  constexpr int ACH = ASZ / 8;                           // 16B chunks/plane
  constexpr int ACH2 = ACH / 2;                          // chunks/(plane,hs)
  constexpr int NPL = ALO ? 2 : 1;                       // staged A planes
  constexpr int NBUF = DBUF ? 2 : 1;
  constexpr int TCH  = BREG ? (KU * NPL * ACH) : (1152 + NPL * ACH);
  constexpr int NI   = (TCH + 255) / 256;
  constexpr int SBH  = 9 * 2 * 64 * 8;                   // h16 per sB buffer
  constexpr int SBSZ = BREG ? 8 : (NBUF * SBH);

  __shared__ h16 sB[SBSZ];
  __shared__ h16 sA[NBUF][KU][NPL][ASZ + 16];            // +16 = zero sentinel

  const int tid  = threadIdx.x;
  const int lane = tid & 63;
  const int wave = tid >> 6;
  const int half = lane >> 5;
  const int col  = lane & 31;
  const int cob  = blockIdx.z;
  const int co0  = cob * 64;
  const int r0img = blockIdx.y * ROWS_COV;

  auto stageA = [&](int ck, int nb, int ku, int cc2) {
    int pl = cc2 / ACH;                  // 0..NPL-1
    int cc = cc2 - pl * ACH;             // linear LDS dest chunk (required)
    // HSPLIT [hs][px] sub-planes; ACH2 % 64 == 0 -> hs wave-uniform.
    int hs  = cc / ACH2;
    int px  = cc - hs * ACH2;
    int iL  = px / (SROWS * W);
    int rem = px - iL * (SROWS * W);
    int rs  = rem / W;
    int pxx = rem - rs * W;
    int grow = r0img + rs - ROFF;
    if constexpr (ROFF == 1) {
      // CLAMP (not skip): all lanes stay active -> no exec divergence.
      grow = grow < 0 ? 0 : (grow >= H ? H - 1 : grow);
    }
    const h16* gp = pl ? Al : Ah;
    int srcA = 16 + (((blockIdx.x * IPB + iL) * KC + ck) * HW + grow * W + pxx) * 16 + hs * 8;
    dma_b16(gp + srcA, &sA[nb][ku][pl][cc * 8]);
  };

  auto STAGE = [&](int ck0, int nb) {
#pragma unroll
    for (int i = 0; i < NI; ++i) {
      int id = tid + i * 256;
      if constexpr (BREG) {
        if (id < TCH) {
          int ku = id / (NPL * ACH);
          stageA(ck0 + ku, nb, ku, id - ku * NPL * ACH);
        }
      } else {
        if (id < 1152) {
          int src = ((ck0 * 9 + (id >> 7)) * KCOB + cob) * 1024 + (id & 127) * 8;
          dma_b16(Wh + src, &sB[nb * SBH + id * 8]);
        } else if (id < TCH) {
          stageA(ck0, nb, 0, id - 1152);
        }
      }
    }
  };

  int scc[MT], ty[MT], tx[MT], img_t[MT], rw0[MT];
#pragma unroll
  for (int t = 0; t < MT; ++t) {
    int gt   = blockIdx.y * (4 * MT) + wave * MT + t;
    int imgL = (gt / TPI) % IPB;
    int img  = blockIdx.x * IPB + gt / TPI;
    int row0 = (gt % TPI) * RPT;
    int y = row0 + (col >> LOGW);
    int x = col & (W - 1);
    img_t[t] = img; rw0[t] = row0; ty[t] = y; tx[t] = x;
    scc[t] = half * ACH2 + (imgL * SROWS + (y - r0img + ROFF)) * W + x;  // chunk
  }

  f32x16 acc[MT][2];
#pragma unroll
  for (int t = 0; t < MT; ++t)
#pragma unroll
    for (int n = 0; n < 2; ++n)
#pragma unroll
      for (int i = 0; i < 16; ++i) acc[t][n][i] = 0.f;

  // zero the halo sentinels + stage stage-0 into buffer 0
  if (tid < NBUF * KU * NPL * 16) {
    int wsl = tid >> 4;                  // [nb][ku][pl] slot
    int pl = wsl % NPL;
    int kq = (wsl / NPL) % KU;
    int nb = wsl / (NPL * KU);
    sA[nb][kq][pl][ASZ + (tid & 15)] = (h16)0.f;
  }
  STAGE(0, 0);
  __syncthreads();

  const int zoff = ASZ + half * 8;   // sentinel (h16 offset)

  int buf = 0;
#pragma unroll 1
  for (int cc = 0; cc < KC; cc += KU) {
    if constexpr (DBUF) {
      if (cc + KU < KC) STAGE(cc + KU, buf ^ 1);   // lands under the tap loops
    }
#pragma unroll
    for (int ku = 0; ku < KU; ++ku) {
      const int ck = cc + ku;
      const h16* bB = &sB[BREG ? 0 : (buf * SBH)];
      const h16* aH = &sA[buf][ku][0][0];
      const h16* aL = ALO ? &sA[buf][ku][NPL - 1][0] : nullptr;
      const h16* bG = Wh + ((size_t)ck * 9 * KCOB + cob) * 1024 + half * 512;

#pragma unroll
      for (int tap = 0; tap < 9; ++tap) {
        const int dy = tap / 3 - 1, dx = tap % 3 - 1;
        const int dsh = dy * W + dx;          // pixel (=chunk) delta
        half8 bh[2];
        if constexpr (BREG) {
          const h16* bt = bG + (size_t)tap * KCOB * 1024;
          bh[0] = *(const half8*)&bt[col * 8];
          bh[1] = *(const half8*)&bt[(32 + col) * 8];
        } else {
#pragma unroll
          for (int n = 0; n < 2; ++n)
            bh[n] = *(const half8*)&bB[((tap * 2 + half) * 64 + n * 32 + col) * 8];
        }
        half8 ah[MT], al[MT];
#pragma unroll
        for (int t = 0; t < MT; ++t) {
          bool v = ((unsigned)(ty[t] + dy) < (unsigned)H) &&
                   ((unsigned)(tx[t] + dx) < (unsigned)W);
          int po = v ? ((scc[t] + dsh) * 8) : zoff;
          ah[t] = *(const half8*)(aH + po);
          if constexpr (ALO) al[t] = *(const half8*)(aL + po);
        }
#pragma unroll
        for (int t = 0; t < MT; ++t)
#pragma unroll
          for (int n = 0; n < 2; ++n) {
            acc[t][n] = __builtin_amdgcn_mfma_f32_32x32x16_f16(ah[t], bh[n], acc[t][n], 0, 0, 0);
            if constexpr (ALO)
              acc[t][n] = __builtin_amdgcn_mfma_f32_32x32x16_f16(al[t], bh[n], acc[t][n], 0, 0, 0);
          }
      }
    }

    if constexpr (DBUF) {
      __syncthreads();   // drains the DMA (vmcnt) + orders buffer swap
      buf ^= 1;
    } else {
      __syncthreads();   // all waves done reading sA/sB
      if (cc + KU < KC) {
        STAGE(cc + KU, 0);
        __syncthreads(); // drains DMA -> buffers hold next stage
      }
    }
  }

#pragma unroll
  for (int n = 0; n < 2; ++n) {
    const int co = co0 + n * 32 + col;
    const float es = bns[co];
    const float eb = fmaf(cb[co], es, bnb[co]);
    const int cko = co >> 4, c16 = co & 15;

    if constexpr (POOL == 0) {
#pragma unroll
      for (int t = 0; t < MT; ++t) {
#pragma unroll
        for (int r = 0; r < 16; ++r) {
          float v = fmaxf(fmaf(acc[t][n][r], es, eb), 0.f);
          int m = (r & 3) + 4 * half + 8 * (r >> 2);
          int y = rw0[t] + (m >> LOGW);
          int x = m & (W - 1);
          size_t oi = 16 + ((size_t)(img_t[t] * KCO + cko) * HW + y * W + x) * 16 + c16;
          h16 hh, ll; split2f(v, hh, ll);
          Oh[oi] = hh;
          if constexpr (OLO) Ol[oi] = ll;
        }
      }
    } else if constexpr (POOL == 1 && RPT == 1) {
      constexpr int HWq = (H / 2) * (W / 2);
#pragma unroll
      for (int tp = 0; tp < MT / 2; ++tp) {
        const int t0 = 2 * tp, t1 = 2 * tp + 1;
        const int yq = rw0[t0] >> 1;
#pragma unroll
        for (int r = 0; r < 16; r += 2) {
          float v00 = fmaxf(fmaf(acc[t0][n][r],     es, eb), 0.f);
          float v01 = fmaxf(fmaf(acc[t0][n][r + 1], es, eb), 0.f);
          float v10 = fmaxf(fmaf(acc[t1][n][r],     es, eb), 0.f);
          float v11 = fmaxf(fmaf(acc[t1][n][r + 1], es, eb), 0.f);
          float mv = fmaxf(fmaxf(v00, v01), fmaxf(v10, v11));
          int xq = ((r & 3) >> 1) + 2 * half + 4 * (r >> 2);
          size_t oi = 16 + ((size_t)(img_t[t0] * KCO + cko) * HWq + yq * (W / 2) + xq) * 16 + c16;
          h16 hh, ll; split2f(mv, hh, ll);
          Oh[oi] = hh;
          if constexpr (OLO) Ol[oi] = ll;
        }
      }
    } else if constexpr (POOL == 1) {
      constexpr int HWq = (H / 2) * (W / 2);
#pragma unroll
      for (int t = 0; t < MT; ++t) {
        const int yq = rw0[t] >> 1;
#pragma unroll
        for (int r = 0; r < 8; r += 2) {
          float v00 = fmaxf(fmaf(acc[t][n][r],     es, eb), 0.f);
          float v01 = fmaxf(fmaf(acc[t][n][r + 1], es, eb), 0.f);
          float v10 = fmaxf(fmaf(acc[t][n][r + 8], es, eb), 0.f);
          float v11 = fmaxf(fmaf(acc[t][n][r + 9], es, eb), 0.f);
          float mv = fmaxf(fmaxf(v00, v01), fmaxf(v10, v11));
          int xq = ((r & 3) >> 1) + 2 * half + 4 * (r >> 2);
          size_t oi = 16 + ((size_t)(img_t[t] * KCO + cko) * HWq + yq * (W / 2) + xq) * 16 + c16;
          h16 hh, ll; split2f(mv, hh, ll);
          Oh[oi] = hh;
          if constexpr (OLO) Ol[oi] = ll;
        }
      }
    } else if constexpr (POOL == 2 && MT == 1) {
      // reuse sA[0] as the reduction scratch (all reads drained by last barrier)
      float* sRd = (float*)&sA[0][0][0][0];
      float s = 0.f;
#pragma unroll
      for (int r = 0; r < 16; ++r)
        s += fmaxf(fmaf(acc[0][n][r], es, eb), 0.f);
      s += __shfl_xor(s, 32, 64);
      if (half == 0) sRd[wave * 64 + n * 32 + col] = s;
    } else if constexpr (POOL == 2) {
      float s = 0.f;
#pragma unroll
      for (int t = 0; t < MT; ++t)
#pragma unroll
        for (int r = 0; r < 16; ++r)
          s += fmaxf(fmaf(acc[t][n][r], es, eb), 0.f);
      s += __shfl_xor(s, 32, 64);
      if (half == 0) feats[(size_t)img_t[0] * 256 + co] = s * (1.f / 64.f);
    }
  }

  if constexpr (POOL == 2 && MT == 1) {
    float* sRd = (float*)&sA[0][0][0][0];
    __syncthreads();
    if (tid < 128) {
      int li = tid >> 6, co_l = tid & 63;
      float s = sRd[(li * 2) * 64 + co_l] + sRd[(li * 2 + 1) * 64 + co_l];
      feats[(size_t)(blockIdx.x * 2 + li) * 256 + co0 + co_l] = s * (1.f / 64.f);
    }
  }
}

// ---------------------------------------------------------------------------
// Batched head GEMM: 32 batch rows/block, one expert per blockIdx.y.
// HEAD=0: plain (store out). HEAD=1: + cls logits/softmax/entropy fused
// (out store dropped; writes o1=logits_e, o2=conf). HEAD=2: + gate2/gate3
// fused (out store dropped; writes o1=scores).
// ---------------------------------------------------------------------------
template<int O, int K, int LN, int RELU, int HEAD>
__global__ __launch_bounds__(256, 4) void gemm_head(
    const float* __restrict__ A, size_t aStrideE,
    const float* __restrict__ Wm, const float* __restrict__ bias,
    const float* __restrict__ g, const float* __restrict__ bb,
    float* __restrict__ out,
    const float* __restrict__ xw1, const float* __restrict__ xb1,
    const float* __restrict__ xw2, const float* __restrict__ xb2,
    float* __restrict__ o1, float* __restrict__ o2)
{
  constexpr int KC  = (O >= 256) ? 32 : 64;
  constexpr int WST = O + 4;
  constexpr int TO  = O / 16;
  __shared__ float sA[KC * 36];
  __shared__ float sW[KC * WST];
  __shared__ float mArr[32], rArr[32];

  const int tid  = threadIdx.x;
  const int lane = tid & 63;
  const int wave = tid >> 6;
  const int e    = blockIdx.y;
  const int b0g  = blockIdx.x * 32;
  const int bl   = (lane & 15) * 2;
  const int ol   = wave * (O / 4) + (lane >> 4) * TO;

  const float* Ae = A + (size_t)e * aStrideE;
  const float* We = Wm + (size_t)e * O * K;

  float acc[2][TO];
#pragma unroll
  for (int i = 0; i < 2; ++i)
#pragma unroll
    for (int j = 0; j < TO; ++j) acc[i][j] = 0.f;

  for (int k0 = 0; k0 < K; k0 += KC) {
    for (int idx = tid; idx < 32 * KC; idx += 256) {
      int kk = idx % KC, bb_ = idx / KC;
      sA[kk * 36 + bb_] = Ae[(size_t)(b0g + bb_) * K + k0 + kk];
    }
    for (int idx = tid; idx < O * KC; idx += 256) {
      int kk = idx % KC, oo = idx / KC;
      sW[kk * WST + oo] = We[(size_t)oo * K + k0 + kk];
    }
    __syncthreads();
#pragma unroll 4
    for (int kk = 0; kk < KC; ++kk) {
      float2 av = *(const float2*)&sA[kk * 36 + bl];
      float a2[2] = {av.x, av.y};
#pragma unroll
      for (int j4 = 0; j4 < TO; j4 += 4) {
        float4 wv = *(const float4*)&sW[kk * WST + ol + j4];
        float w4[4] = {wv.x, wv.y, wv.z, wv.w};
#pragma unroll
        for (int i = 0; i < 2; ++i)
#pragma unroll
          for (int jj = 0; jj < 4; ++jj)
            acc[i][j4 + jj] = fmaf(a2[i], w4[jj], acc[i][j4 + jj]);
      }
    }
    __syncthreads();
  }

  const float* bi = bias + (size_t)e * O;
#pragma unroll
  for (int i = 0; i < 2; ++i)
#pragma unroll
    for (int j = 0; j < TO; ++j) acc[i][j] += bi[ol + j];

  if constexpr (LN) {
    float* redS = sA;
    float* redQ = sA + 512;
    const int grp = wave * 4 + (lane >> 4);
#pragma unroll
    for (int i = 0; i < 2; ++i) {
      float s = 0.f, q = 0.f;
#pragma unroll
      for (int j = 0; j < TO; ++j) { s += acc[i][j]; q += acc[i][j] * acc[i][j]; }
      redS[(bl + i) * 16 + grp] = s;
      redQ[(bl + i) * 16 + grp] = q;
    }
    __syncthreads();
    if (tid < 32) {
      float s = 0.f, q = 0.f;
#pragma unroll
      for (int gi = 0; gi < 16; ++gi) { s += redS[tid * 16 + gi]; q += redQ[tid * 16 + gi]; }
      float mean = s * (1.f / O);
      float var  = q * (1.f / O) - mean * mean;
      mArr[tid] = mean;
      rArr[tid] = rsqrtf(var + 1e-5f);
    }
    __syncthreads();
    const float* gp  = g + (size_t)e * O;
    const float* bbp = bb + (size_t)e * O;
#pragma unroll
    for (int i = 0; i < 2; ++i) {
      float mean = mArr[bl + i], rstd = rArr[bl + i];
#pragma unroll
      for (int j = 0; j < TO; ++j)
        acc[i][j] = (acc[i][j] - mean) * rstd * gp[ol + j] + bbp[ol + j];
    }
  }
  if constexpr (RELU) {
#pragma unroll
    for (int i = 0; i < 2; ++i)
#pragma unroll
      for (int j = 0; j < TO; ++j) acc[i][j] = fmaxf(acc[i][j], 0.f);
  }

  if constexpr (HEAD == 0) {
#pragma unroll
    for (int i = 0; i < 2; ++i) {
      float* op = out + ((size_t)e * 512 + b0g + bl + i) * O + ol;
#pragma unroll
      for (int j4 = 0; j4 < TO; j4 += 4)
        *(float4*)(op + j4) = make_float4(acc[i][j4], acc[i][j4 + 1], acc[i][j4 + 2], acc[i][j4 + 3]);
    }
  } else if constexpr (HEAD == 1) {
    // ---- fused cls: logits (lg), softmax entropy -> conf. emb not stored.
    float* et = sW;                      // 32 x WST tile (sW is free here)
    __syncthreads();                     // all sW reads of the K loop done
#pragma unroll
    for (int i = 0; i < 2; ++i)
#pragma unroll
      for (int j = 0; j < TO; ++j) et[(bl + i) * WST + ol + j] = acc[i][j];
    __syncthreads();
    // 320 work items (32 b x 10 o) on 256 threads: block-stride loop.
    for (int idx = tid; idx < 320; idx += 256) {
      int b = idx / 10, o = idx - (idx / 10) * 10;
      const float* wp = xw1 + ((size_t)e * 10 + o) * O;
      const float* er = et + b * WST;
      float s = 0.f;
      for (int c = 0; c < O; ++c) s = fmaf(er[c], wp[c], s);
      s += xb1[e * 10 + o];
      o1[((size_t)(b0g + b) * 16 + e) * 10 + o] = s;
      sA[b * 10 + o] = s;
    }
    __syncthreads();
    if (tid < 32) {
      int b = tid;
      float l0[10];
#pragma unroll
      for (int o = 0; o < 10; ++o) l0[o] = sA[b * 10 + o];
      float m = l0[0];
#pragma unroll
      for (int o = 1; o < 10; ++o) m = fmaxf(m, l0[o]);
      float p0[10], sum = 0.f;
#pragma unroll
      for (int o = 0; o < 10; ++o) { p0[o] = expf(l0[o] - m); sum += p0[o]; }
      float inv = 1.f / sum, ent = 0.f;
#pragma unroll
      for (int o = 0; o < 10; ++o) { float pp = p0[o] * inv; ent -= pp * logf(pp + 1e-12f); }
      o2[(size_t)(b0g + b) * 16 + e] = -ent;
    }
  } else {
    // ---- fused gate2 (1024 parallel 64-dots) + gate3 -> scores. g1 not stored.
    float* gt = sW;                      // 32 x WST tile
    __syncthreads();
#pragma unroll
    for (int i = 0; i < 2; ++i)
#pragma unroll
      for (int j = 0; j < TO; ++j) gt[(bl + i) * WST + ol + j] = acc[i][j];
    __syncthreads();
#pragma unroll
    for (int p = 0; p < 4; ++p) {
      int idx = tid + p * 256;           // 1024 (b, o2) pairs
      int b = idx >> 5, o2i = idx & 31;
      const float* wr = xw1 + ((size_t)e * 32 + o2i) * 64;
      const float* gr = gt + b * WST;
      float s = 0.f;
      for (int c = 0; c < 64; ++c) s = fmaf(gr[c], wr[c], s);
      sA[b * 36 + o2i] = fmaxf(s + xb1[e * 32 + o2i], 0.f);
    }
    __syncthreads();
    if (tid < 32) {
      int b = tid;
      const float* w3p = xw2 + e * 32;
      float s = 0.f;
#pragma unroll
      for (int oo = 0; oo < 32; ++oo) s = fmaf(sA[b * 36 + oo], w3p[oo], s);
      o1[(size_t)(b0g + b) * 16 + e] = s + xb2[e];
    }
  }
}

__global__ void routing_k(const float* __restrict__ scores, const float* __restrict__ conf,
                          const float* __restrict__ logits_e, float* __restrict__ out)
{
  __shared__ int t2[512];
  __shared__ int chs[512];
  const int tid = threadIdx.x;

  if (tid < 512) {
    int b = tid;
    float v0 = -3.4e38f, v1 = -3.4e38f;
    int i0 = 0, i1 = 0;
#pragma unroll
    for (int e = 0; e < 16; ++e) {
      float s = scores[b * 16 + e];
      float c = conf[b * 16 + e];
      float v = 0.7f * s + 0.3f * c - 0.125f;
      out[5120 + b * 16 + e] = v;
      if (v > v0) { v1 = v0; i1 = i0; v0 = v; i0 = e; }
      else if (v > v1) { v1 = v; i1 = e; }
    }
    t2[b] = i0 | (i1 << 8);
  }
  __syncthreads();

  if (tid < 64) {
    int lane = tid;
    int cnt = 0;
    int pk[8];
#pragma unroll
    for (int k = 0; k < 8; ++k) pk[k] = t2[k * 64 + lane];
#pragma unroll 1
    for (int k = 0; k < 8; ++k) {
      for (int j = 0; j < 64; ++j) {
        int pair = __shfl(pk[k], j, 64);
        int i0 = pair & 0xff, i1 = (pair >> 8) & 0xff;
        int c0 = __shfl(cnt, i0, 64);
        int c1 = __shfl(cnt, i1, 64);
        int ch = (c0 < 64) ? i0 : ((c1 < 64) ? i1 : ((c0 <= c1) ? i0 : i1));
        cnt += (lane == ch) ? 1 : 0;
        if (lane == 0) chs[k * 64 + j] = ch;
      }
    }
  }
  __syncthreads();

  if (tid < 512) {
    int b = tid;
    int ch = chs[b];
#pragma unroll
    for (int e = 0; e < 16; ++e)
      out[13312 + b * 16 + e] = (e == ch) ? 1.0f : 0.0f;
#pragma unroll
    for (int o = 0; o < 10; ++o)
      out[b * 10 + o] = logits_e[((size_t)b * 16 + ch) * 10 + o];
  }
}

// ============================================================================
extern "C" void kernel_launch(void* const* d_in, const int* in_sizes, int n_in,
                              void* d_out, int out_size, void* d_ws, size_t ws_size,
                              hipStream_t stream) {
  (void)in_sizes; (void)n_in; (void)out_size; (void)ws_size;

  const float* x = (const float*)d_in[0];
  const float *cw[6], *cbv[6], *bsv[6], *bbv[6];
  for (int i = 0; i < 6; ++i) {
    cw[i]  = (const float*)d_in[1 + 4 * i];
    cbv[i] = (const float*)d_in[2 + 4 * i];
    bsv[i] = (const float*)d_in[3 + 4 * i];
    bbv[i] = (const float*)d_in[4 + 4 * i];
  }
  const float* gate_w1  = (const float*)d_in[25];
  const float* gate_b1  = (const float*)d_in[26];
  const float* gate_g1  = (const float*)d_in[27];
  const float* gate_bb1 = (const float*)d_in[28];
  const float* gate_w2  = (const float*)d_in[29];
  const float* gate_b2  = (const float*)d_in[30];
  const float* gate_w3  = (const float*)d_in[31];
  const float* gate_b3  = (const float*)d_in[32];
  const float* exp_w1   = (const float*)d_in[33];
  const float* exp_b1   = (const float*)d_in[34];
  const float* exp_g1   = (const float*)d_in[35];
  const float* exp_bb1  = (const float*)d_in[36];
  const float* exp_w2   = (const float*)d_in[37];
  const float* exp_b2   = (const float*)d_in[38];
  const float* exp_g2   = (const float*)d_in[39];
  const float* exp_bb2  = (const float*)d_in[40];
  const float* exp_w3   = (const float*)d_in[41];
  const float* exp_b3   = (const float*)d_in[42];
  const float* cls_w    = (const float*)d_in[43];
  const float* cls_b    = (const float*)d_in[44];

  char* wsb = (char*)d_ws;
  const size_t off_wt1t = 0;
  const size_t off_whi  = 6912;
  const size_t off_Phi  = 4578048;
  const size_t off_Plo  = 71687168;
  const size_t off_Qhi  = 138796288;
  const size_t off_Qlo  = 155573760;
  const size_t off_feats= 172351232;
  const size_t off_h1   = 138796288 + 512;
  const size_t off_h2   = off_h1 + 8388608;
  const size_t off_emb  = off_h2 + 4194304;
  const size_t off_g1   = off_emb + 4194304;
  const size_t off_lg   = off_g1 + 2097152;
  const size_t off_conf = off_lg + 327680;
  const size_t off_sc   = off_conf + 32768;

  float* wt1t = (float*)(wsb + off_wt1t);
  h16* whi = (h16*)(wsb + off_whi);
  h16* Phi = (h16*)(wsb + off_Phi);
  h16* Plo = (h16*)(wsb + off_Plo);
  h16* Qhi = (h16*)(wsb + off_Qhi);
  h16* Qlo = (h16*)(wsb + off_Qlo);
  float* feats = (float*)(wsb + off_feats);
  float* h1 = (float*)(wsb + off_h1);
  float* h2 = (float*)(wsb + off_h2);
  float* emb = (float*)(wsb + off_emb);
  float* lg = (float*)(wsb + off_lg);
  float* conf = (float*)(wsb + off_conf);
  float* sc = (float*)(wsb + off_sc);

  const size_t wo2 = 0;
  const size_t wo3 = 36864;
  const size_t wo4 = 110592;
  const size_t wo5 = 258048;
  const size_t wo6 = 552960;

  // ---- fused prep (pads + wt1 transpose + all weight splits) ----
  prep_all_k<<<4471, 256, 0, stream>>>(cw[0], cw[1], cw[2], cw[3], cw[4], cw[5],
                                       wt1t, whi, Phi, Plo, Qhi, Qlo);

  // ---- trunk (hi-only fp16 activations throughout) ----
  conv1_k<<<512, 256, 0, stream>>>(x, wt1t, cbv[0], bsv[0], bbv[0], Phi);
  // <H, W, CIN, COUT, MT, POOL, OCC, DBUF, BREG, KU, ALO, OLO>
  conv_mfma<32, 32, 64, 64, 2, 1, 3, 1, 1, 1, 0, 0><<<dim3(512, 4, 1), 256, 0, stream>>>(
      Phi, Phi, whi + wo2, cbv[1], bsv[1], bbv[1], Qhi, Qlo, nullptr);
  conv_mfma<16, 16, 64, 128, 2, 0, 3, 1, 1, 1, 0, 0><<<dim3(512, 1, 2), 256, 0, stream>>>(
      Qhi, Qhi, whi + wo3, cbv[2], bsv[2], bbv[2], Phi, Plo, nullptr);
  conv_mfma<16, 16, 128, 128, 2, 1, 3, 1, 1, 1, 0, 0><<<dim3(512, 1, 2), 256, 0, stream>>>(
      Phi, Phi, whi + wo4, cbv[3], bsv[3], bbv[3], Qhi, Qlo, nullptr);
  conv_mfma<8, 8, 128, 256, 1, 0, 3, 1, 1, 1, 0, 0><<<dim3(256, 1, 4), 256, 0, stream>>>(
      Qhi, Qhi, whi + wo5, cbv[4], bsv[4], bbv[4], Phi, Plo, nullptr);
  conv_mfma<8, 8, 256, 256, 1, 2, 4, 1, 1, 2, 0, 1><<<dim3(256, 1, 4), 256, 0, stream>>>(
      Phi, Phi, whi + wo6, cbv[5], bsv[5], bbv[5], nullptr, nullptr, feats);

  // ---- experts + gates (heads fused into gate1/exp3 epilogues) ----
  gemm_head<256, 256, 1, 1, 0><<<dim3(16, 16), 256, 0, stream>>>(
      feats, (size_t)0, exp_w1, exp_b1, exp_g1, exp_bb1, h1,
      nullptr, nullptr, nullptr, nullptr, nullptr, nullptr);
  gemm_head<64, 256, 1, 1, 2><<<dim3(16, 16), 256, 0, stream>>>(
      feats, (size_t)0, gate_w1, gate_b1, gate_g1, gate_bb1, nullptr,
      gate_w2, gate_b2, gate_w3, gate_b3, sc, nullptr);
  gemm_head<128, 256, 1, 1, 0><<<dim3(16, 16), 256, 0, stream>>>(
      h1, (size_t)512 * 256, exp_w2, exp_b2, exp_g2, exp_bb2, h2,
      nullptr, nullptr, nullptr, nullptr, nullptr, nullptr);
  gemm_head<128, 128, 0, 0, 1><<<dim3(16, 16), 256, 0, stream>>>(
      h2, (size_t)512 * 128, exp_w3, exp_b3, nullptr, nullptr, emb,
      cls_w, cls_b, nullptr, nullptr, lg, conf);

  // ---- routing + outputs ----
  routing_k<<<1, 512, 0, stream>>>(sc, conf, lg, (float*)d_out);
}